// Round 1
// 1533.930 us; speedup vs baseline: 1.1635x; 1.1635x over previous
//
#include <hip/hip_runtime.h>
#include <math.h>

#define NN 100000
#define EE 1600000
#define NFEATC 512
#define NHIDC 256
#define NCC 64
#define ALPHA_C 0.1f
#define NSLOPE_C 0.2f

typedef __attribute__((ext_vector_type(8))) short short8;
typedef __attribute__((ext_vector_type(4))) short short4v;
typedef __attribute__((ext_vector_type(4))) float floatx4;

__device__ __forceinline__ short f2bf(float f) {
    unsigned u = __float_as_uint(f);
    unsigned r = (u + 0x7FFFu + ((u >> 16) & 1u)) >> 16;   // RNE
    return (short)r;
}
__device__ __forceinline__ float bf2f(short s) {
    return __uint_as_float(((unsigned)(unsigned short)s) << 16);
}

// ---------------- W_in transpose-cast: W[512][256] fp32 -> WT[256][512] bf16 ----------------
__global__ __launch_bounds__(256)
void castWT_kernel(const float* __restrict__ W, short* __restrict__ WT, int K, int Ncols)
{
    int k = blockIdx.x;
    int n = threadIdx.x;
    if (k < K && n < Ncols)
        WT[(size_t)n * K + k] = f2bf(W[(size_t)k * Ncols + n]);
}

// ---------------- elementwise fp32 -> bf16 cast (vectorized 4/thread) ----------------
__global__ __launch_bounds__(256)
void cast_bf_kernel(const float* __restrict__ in, short* __restrict__ out, int n4)
{
    int i = blockIdx.x * 256 + threadIdx.x;
    if (i >= n4) return;
    float4 v = reinterpret_cast<const float4*>(in)[i];
    short4v o;
    o[0] = f2bf(v.x); o[1] = f2bf(v.y); o[2] = f2bf(v.z); o[3] = f2bf(v.w);
    reinterpret_cast<short4v*>(out)[i] = o;
}

// ---------------- gemm1: h1 = elu(x @ W_in)  via bf16 MFMA ----------------
__global__ __launch_bounds__(256)
void gemm1_mfma_kernel(const float* __restrict__ x, const short* __restrict__ WT,
                       float* __restrict__ h1, int M)
{
    __shared__ short As[128][40];
    __shared__ short Bs[256][40];
    const int tid = threadIdx.x;
    const int bm = blockIdx.x * 128;
    const int wave = tid >> 6;
    const int lane = tid & 63;
    const int wm = wave >> 1;
    const int wn = wave & 1;
    const int l16 = lane & 15;
    const int quad = lane >> 4;

    floatx4 acc[4][8];
    #pragma unroll
    for (int i = 0; i < 4; ++i)
        #pragma unroll
        for (int j = 0; j < 8; ++j)
            acc[i][j] = (floatx4){0.f, 0.f, 0.f, 0.f};

    const int ar = tid >> 1;
    const int ah = tid & 1;
    const int xrow = bm + ar;
    const float* xp = x + (size_t)xrow * NFEATC + ah * 16;
    const short* wp = WT + (size_t)tid * NFEATC;

    for (int kt = 0; kt < NFEATC; kt += 32) {
        float4 a0, a1, a2, a3;
        if (xrow < M) {
            a0 = *reinterpret_cast<const float4*>(xp + kt + 0);
            a1 = *reinterpret_cast<const float4*>(xp + kt + 4);
            a2 = *reinterpret_cast<const float4*>(xp + kt + 8);
            a3 = *reinterpret_cast<const float4*>(xp + kt + 12);
        } else {
            a0 = a1 = a2 = a3 = make_float4(0.f, 0.f, 0.f, 0.f);
        }
        const short8* wq = reinterpret_cast<const short8*>(wp + kt);
        short8 b0 = wq[0], b1 = wq[1], b2 = wq[2], b3 = wq[3];

        short8 s0, s1;
        s0[0] = f2bf(a0.x); s0[1] = f2bf(a0.y); s0[2] = f2bf(a0.z); s0[3] = f2bf(a0.w);
        s0[4] = f2bf(a1.x); s0[5] = f2bf(a1.y); s0[6] = f2bf(a1.z); s0[7] = f2bf(a1.w);
        s1[0] = f2bf(a2.x); s1[1] = f2bf(a2.y); s1[2] = f2bf(a2.z); s1[3] = f2bf(a2.w);
        s1[4] = f2bf(a3.x); s1[5] = f2bf(a3.y); s1[6] = f2bf(a3.z); s1[7] = f2bf(a3.w);

        __syncthreads();
        *reinterpret_cast<short8*>(&As[ar][ah * 16 + 0]) = s0;
        *reinterpret_cast<short8*>(&As[ar][ah * 16 + 8]) = s1;
        *reinterpret_cast<short8*>(&Bs[tid][0])  = b0;
        *reinterpret_cast<short8*>(&Bs[tid][8])  = b1;
        *reinterpret_cast<short8*>(&Bs[tid][16]) = b2;
        *reinterpret_cast<short8*>(&Bs[tid][24]) = b3;
        __syncthreads();

        short8 af[4], bfr[8];
        #pragma unroll
        for (int mi = 0; mi < 4; ++mi)
            af[mi] = *reinterpret_cast<const short8*>(&As[wm * 64 + mi * 16 + l16][quad * 8]);
        #pragma unroll
        for (int ni = 0; ni < 8; ++ni)
            bfr[ni] = *reinterpret_cast<const short8*>(&Bs[wn * 128 + ni * 16 + l16][quad * 8]);
        #pragma unroll
        for (int mi = 0; mi < 4; ++mi)
            #pragma unroll
            for (int ni = 0; ni < 8; ++ni)
                acc[mi][ni] = __builtin_amdgcn_mfma_f32_16x16x32_bf16(af[mi], bfr[ni], acc[mi][ni], 0, 0, 0);
    }

    #pragma unroll
    for (int mi = 0; mi < 4; ++mi) {
        #pragma unroll
        for (int r = 0; r < 4; ++r) {
            int row = bm + wm * 64 + mi * 16 + quad * 4 + r;
            if (row >= M) continue;
            float* outp = h1 + (size_t)row * NHIDC + wn * 128 + l16;
            #pragma unroll
            for (int ni = 0; ni < 8; ++ni) {
                float v = acc[mi][ni][r];
                v = (v > 0.f) ? v : (expf(v) - 1.f);
                outp[ni * 16] = v;
            }
        }
    }
}

// ---------------- GEMM: C = act(A@B + bias), tile 64x64, KT=16, 256 thr, 4x4 micro ----------------
template<int ACT>
__global__ __launch_bounds__(256)
void gemm_kernel(const float* __restrict__ A, const float* __restrict__ B,
                 const float* __restrict__ bias, float* __restrict__ C,
                 int M, int K, int Ncols)
{
    __shared__ float As[16][68];
    __shared__ float Bs[16][64];
    const int tid = threadIdx.x;
    const int bm = blockIdx.x * 64;
    const int bn = blockIdx.y * 64;
    const int m0 = (tid & 15) * 4;
    const int n0 = (tid >> 4) * 4;
    float acc[4][4] = {};

    const int am = bm + (tid >> 2);
    const int ak = (tid & 3) * 4;
    const int bk = tid >> 4;
    const int bn4 = bn + (tid & 15) * 4;

    for (int kt = 0; kt < K; kt += 16) {
        float4 av;
        if (am < M) av = *reinterpret_cast<const float4*>(A + (size_t)am * K + kt + ak);
        else        av = make_float4(0.f, 0.f, 0.f, 0.f);
        float4 bv = *reinterpret_cast<const float4*>(B + (size_t)(kt + bk) * Ncols + bn4);
        __syncthreads();
        As[ak + 0][tid >> 2] = av.x;
        As[ak + 1][tid >> 2] = av.y;
        As[ak + 2][tid >> 2] = av.z;
        As[ak + 3][tid >> 2] = av.w;
        *reinterpret_cast<float4*>(&Bs[bk][(tid & 15) * 4]) = bv;
        __syncthreads();
        #pragma unroll
        for (int k = 0; k < 16; ++k) {
            float4 a4 = *reinterpret_cast<const float4*>(&As[k][m0]);
            float4 b4 = *reinterpret_cast<const float4*>(&Bs[k][n0]);
            float a_[4] = {a4.x, a4.y, a4.z, a4.w};
            float b_[4] = {b4.x, b4.y, b4.z, b4.w};
            #pragma unroll
            for (int i = 0; i < 4; ++i)
                #pragma unroll
                for (int j = 0; j < 4; ++j)
                    acc[i][j] = fmaf(a_[i], b_[j], acc[i][j]);
        }
    }

    float bvals[4] = {0.f, 0.f, 0.f, 0.f};
    if (bias) {
        bvals[0] = bias[bn + n0 + 0]; bvals[1] = bias[bn + n0 + 1];
        bvals[2] = bias[bn + n0 + 2]; bvals[3] = bias[bn + n0 + 3];
    }
    #pragma unroll
    for (int i = 0; i < 4; ++i) {
        int r = bm + m0 + i;
        if (r >= M) break;
        float v[4];
        #pragma unroll
        for (int j = 0; j < 4; ++j) {
            float t = acc[i][j] + bvals[j];
            if (ACT == 1) t = (t > 0.f) ? t : (expf(t) - 1.f);
            v[j] = t;
        }
        float4 o = make_float4(v[0], v[1], v[2], v[3]);
        *reinterpret_cast<float4*>(C + (size_t)r * Ncols + bn + n0) = o;
    }
}

// ---------------- per-node attention scalars: el, er ----------------
__global__ __launch_bounds__(256)
void attn_kernel(const float* __restrict__ h, const float* __restrict__ attn_l,
                 const float* __restrict__ attn_r, float* __restrict__ el, float* __restrict__ er)
{
    int node = blockIdx.x * 4 + (threadIdx.x >> 6);
    int lane = threadIdx.x & 63;
    if (node >= NN) return;
    float v = h[(size_t)node * 64 + lane];
    float lr = (v > 0.f) ? v : NSLOPE_C * v;
    float a = lr * attn_l[lane];
    float b = lr * attn_r[lane];
    #pragma unroll
    for (int m = 1; m < 64; m <<= 1) {
        a += __shfl_xor(a, m);
        b += __shfl_xor(b, m);
    }
    if (lane == 0) { el[node] = a; er[node] = b; }
}

// ---------------- CSR build ----------------
__global__ __launch_bounds__(256)
void count_kernel(const int* __restrict__ dst, int* __restrict__ cnt)
{
    int e = blockIdx.x * 256 + threadIdx.x;
    if (e < EE) atomicAdd(cnt + dst[e], 1);
}

__global__ __launch_bounds__(1024)
void scan_kernel(const int* __restrict__ cnt, int* __restrict__ row, int* __restrict__ cur)
{
    __shared__ int sums[1024];
    int t = threadIdx.x;
    const int CH = (NN + 1023) / 1024;
    int lo = t * CH, hi = min(lo + CH, NN);
    int s = 0;
    for (int i = lo; i < hi; ++i) s += cnt[i];
    sums[t] = s;
    __syncthreads();
    for (int off = 1; off < 1024; off <<= 1) {
        int add = (t >= off) ? sums[t - off] : 0;
        __syncthreads();
        sums[t] += add;
        __syncthreads();
    }
    int running = sums[t] - s;
    for (int i = lo; i < hi; ++i) {
        row[i] = running;
        cur[i] = running;
        running += cnt[i];
    }
    if (t == 1023) row[NN] = sums[1023];
}

// bucket: scatter src index + original edge weight into CSR order (by dst)
__global__ __launch_bounds__(256)
void bucket_kernel(const int* __restrict__ src, const int* __restrict__ dst,
                   const float* __restrict__ wts, int* __restrict__ cur,
                   int* __restrict__ csr_src, float* __restrict__ csr_wts)
{
    int e = blockIdx.x * 256 + threadIdx.x;
    if (e >= EE) return;
    int d = dst[e];
    int pos = atomicAdd(cur + d, 1);
    csr_src[pos] = src[e];
    csr_wts[pos] = wts[e];
}

// ---------------- edge computation in CSR (dst-grouped) order ----------------
// dst-side rows (h[d], hl[d], er[d]) live in registers once per node; only the
// src side gathers randomly. deg_dst accumulated in-register (no atomics).
__global__ __launch_bounds__(256)
void edge2_kernel(const int* __restrict__ row, const int* __restrict__ csr_src,
                  const float* __restrict__ csr_wts,
                  const float* __restrict__ h, const float* __restrict__ hl,
                  const float* __restrict__ el, const float* __restrict__ er,
                  const float* __restrict__ s_attn, const float* __restrict__ beta,
                  const float* __restrict__ aw,
                  float* __restrict__ ew, float* __restrict__ deg_s,
                  float* __restrict__ deg_d, float* __restrict__ lp_part)
{
    int node = blockIdx.x * 4 + (threadIdx.x >> 6);
    int lane = threadIdx.x & 63;
    int sub = lane >> 4;      // 4 edges in flight per wave
    int f = lane & 15;        // 16 lanes x float4 = full 64-feature row
    float lp_p = 0.f;
    if (node < NN) {
        int b = row[node], en = row[node + 1];
        const float4 hd = *reinterpret_cast<const float4*>(h  + (size_t)node * 64 + f * 4);
        const float4 ld = *reinterpret_cast<const float4*>(hl + (size_t)node * 64 + f * 4);
        const float4 sa = *reinterpret_cast<const float4*>(s_attn + f * 4);
        float erd = er[node];
        float betaw = 2.f / (expf(-beta[0]) + 1.f);
        float a0 = aw[0], a1 = aw[1];
        float mxw = fmaxf(a0, a1);
        float e0 = expf(a0 - mxw), e1 = expf(a1 - mxw);
        float inv = 1.f / (e0 + e1);
        float w0 = e0 * inv, w1 = e1 * inv;
        float degd = 0.f;
        for (int e = b + sub; e < en; e += 4) {
            int s = csr_src[e];
            const float4 hs = *reinterpret_cast<const float4*>(h  + (size_t)s * 64 + f * 4);
            const float4 ls = *reinterpret_cast<const float4*>(hl + (size_t)s * 64 + f * 4);
            float se_p  = ls.x * sa.x * ld.x + ls.y * sa.y * ld.y
                        + ls.z * sa.z * ld.z + ls.w * sa.w * ld.w;
            float dot_p = ls.x * ld.x + ls.y * ld.y + ls.z * ld.z + ls.w * ld.w;
            float dx = hs.x - hd.x, dy = hs.y - hd.y, dz = hs.z - hd.z, dw = hs.w - hd.w;
            float sdf_p = dx * dx + dy * dy + dz * dz + dw * dw;
            float ex = ls.x - ld.x, ey = ls.y - ld.y, ez = ls.z - ld.z, ec = ls.w - ld.w;
            float sds_p = ex * ex + ey * ey + ez * ez + ec * ec;
            #pragma unroll
            for (int m = 1; m < 16; m <<= 1) {
                se_p  += __shfl_xor(se_p, m);
                dot_p += __shfl_xor(dot_p, m);
                sdf_p += __shfl_xor(sdf_p, m);
                sds_p += __shfl_xor(sds_p, m);
            }
            if (f == 0) {
                float evv = el[s] + erd + se_p;
                float dd = w0 * sdf_p + w1 * sds_p;
                float v = expf(evv - betaw * dd) + 1e-9f;
                ew[e] = v;
                atomicAdd(deg_s + s, v);
                degd += v;
                lp_p += dot_p * csr_wts[e];
            }
        }
        #pragma unroll
        for (int m = 16; m < 64; m <<= 1) degd += __shfl_xor(degd, m);
        if (lane == 0) deg_d[node] = degd;
    }
    // lp block reduction (lp_p nonzero only on f==0 lanes)
    #pragma unroll
    for (int m = 16; m < 64; m <<= 1) lp_p += __shfl_xor(lp_p, m);
    __shared__ float lred[4];
    if ((threadIdx.x & 63) == 0) lred[threadIdx.x >> 6] = lp_p;
    __syncthreads();
    if (threadIdx.x == 0) lp_part[blockIdx.x] = lred[0] + lred[1] + lred[2] + lred[3];
}

// ---------------- reduce lp partials ----------------
__global__ __launch_bounds__(256)
void reduce_kernel(const float* __restrict__ part, int n, float* __restrict__ out)
{
    float s = 0.f;
    for (int i = threadIdx.x; i < n; i += 256) s += part[i];
    #pragma unroll
    for (int m = 1; m < 64; m <<= 1) s += __shfl_xor(s, m);
    __shared__ float sd[4];
    if ((threadIdx.x & 63) == 0) sd[threadIdx.x >> 6] = s;
    __syncthreads();
    if (threadIdx.x == 0) out[0] = sd[0] + sd[1] + sd[2] + sd[3];
}

// ---------------- edge normalization, CSR order (sequential) ----------------
__global__ __launch_bounds__(256)
void wnorm_csr_kernel(const int* __restrict__ row, const int* __restrict__ csr_src,
                      const float* __restrict__ ew, const float* __restrict__ deg_s,
                      const float* __restrict__ deg_d, const float* __restrict__ theta,
                      float* __restrict__ csr_w)
{
    int node = blockIdx.x * 16 + (threadIdx.x >> 4);
    int f = threadIdx.x & 15;
    if (node >= NN) return;
    int b = row[node], en = row[node + 1];
    float perm = 1e-9f / (expf(-theta[0]) + 1.f);
    float dr = rsqrtf(deg_d[node]);
    for (int e = b + f; e < en; e += 16) {
        float v = ew[e] * rsqrtf(deg_s[csr_src[e]]) * dr + perm;
        csr_w[e] = (1.0f - ALPHA_C) * v;
    }
}

// ---------------- propagation (bf16 gather, fp32 accumulate) ----------------
// fin is bf16 [NN][64]. 8 lanes x short8 (16 B) per edge row; 8 edges in flight.
// FINAL=0: store bf16 (next iteration's gather source); FINAL=1: fused
// elu + log_softmax epilogue writing the output directly.
template<int FINAL>
__global__ __launch_bounds__(256)
void prop_kernel(const short* __restrict__ fin, const float* __restrict__ h,
                 const int* __restrict__ row, const int* __restrict__ csr_src,
                 const float* __restrict__ csr_w,
                 short* __restrict__ foutb, float* __restrict__ outf)
{
    int node = blockIdx.x * 4 + (threadIdx.x >> 6);
    int lane = threadIdx.x & 63;
    int sub = lane >> 3;   // 8 edges in flight
    int f = lane & 7;      // 8 features per lane
    if (node >= NN) return;
    int b = row[node], en = row[node + 1];
    float acc[8] = {};
    for (int e = b + sub; e < en; e += 8) {
        int s = csr_src[e];
        float wv = csr_w[e];
        short8 v = *reinterpret_cast<const short8*>(fin + (size_t)s * 64 + f * 8);
        #pragma unroll
        for (int i = 0; i < 8; ++i)
            acc[i] = fmaf(wv, bf2f(v[i]), acc[i]);
    }
    #pragma unroll
    for (int m = 8; m < 64; m <<= 1)
        #pragma unroll
        for (int i = 0; i < 8; ++i)
            acc[i] += __shfl_xor(acc[i], m);
    if (sub == 0) {
        const float4 h0 = *reinterpret_cast<const float4*>(h + (size_t)node * 64 + f * 8 + 0);
        const float4 h1v = *reinterpret_cast<const float4*>(h + (size_t)node * 64 + f * 8 + 4);
        float o[8];
        o[0] = fmaf(ALPHA_C, h0.x, acc[0]);
        o[1] = fmaf(ALPHA_C, h0.y, acc[1]);
        o[2] = fmaf(ALPHA_C, h0.z, acc[2]);
        o[3] = fmaf(ALPHA_C, h0.w, acc[3]);
        o[4] = fmaf(ALPHA_C, h1v.x, acc[4]);
        o[5] = fmaf(ALPHA_C, h1v.y, acc[5]);
        o[6] = fmaf(ALPHA_C, h1v.z, acc[6]);
        o[7] = fmaf(ALPHA_C, h1v.w, acc[7]);
        if (!FINAL) {
            short8 ob;
            #pragma unroll
            for (int i = 0; i < 8; ++i) ob[i] = f2bf(o[i]);
            *reinterpret_cast<short8*>(foutb + (size_t)node * 64 + f * 8) = ob;
        } else {
            // fused: out = log_softmax(elu(o)) across the 64 features (8 lanes x 8)
            float ev[8];
            #pragma unroll
            for (int i = 0; i < 8; ++i)
                ev[i] = (o[i] > 0.f) ? o[i] : (expf(o[i]) - 1.f);
            float mx = ev[0];
            #pragma unroll
            for (int i = 1; i < 8; ++i) mx = fmaxf(mx, ev[i]);
            #pragma unroll
            for (int m = 1; m < 8; m <<= 1) mx = fmaxf(mx, __shfl_xor(mx, m));
            float s = 0.f;
            #pragma unroll
            for (int i = 0; i < 8; ++i) s += expf(ev[i] - mx);
            #pragma unroll
            for (int m = 1; m < 8; m <<= 1) s += __shfl_xor(s, m);
            float ls = mx + logf(s);
            float4 o0 = make_float4(ev[0] - ls, ev[1] - ls, ev[2] - ls, ev[3] - ls);
            float4 o1 = make_float4(ev[4] - ls, ev[5] - ls, ev[6] - ls, ev[7] - ls);
            *reinterpret_cast<float4*>(outf + (size_t)node * 64 + f * 8 + 0) = o0;
            *reinterpret_cast<float4*>(outf + (size_t)node * 64 + f * 8 + 4) = o1;
        }
    }
}

extern "C" void kernel_launch(void* const* d_in, const int* in_sizes, int n_in,
                              void* d_out, int out_size, void* d_ws, size_t ws_size,
                              hipStream_t stream)
{
    const float* x      = (const float*)d_in[0];
    const int*   src    = (const int*)d_in[1];
    const int*   dst    = (const int*)d_in[2];
    const float* wts    = (const float*)d_in[3];
    const float* latp   = (const float*)d_in[4];
    const float* W_in   = (const float*)d_in[5];
    const float* W_out  = (const float*)d_in[6];
    const float* Ws1    = (const float*)d_in[7];
    const float* b1     = (const float*)d_in[8];
    const float* Ws2    = (const float*)d_in[9];
    const float* b2     = (const float*)d_in[10];
    const float* attn_l = (const float*)d_in[11];
    const float* attn_r = (const float*)d_in[12];
    const float* s_attn = (const float*)d_in[13];
    const float* beta   = (const float*)d_in[14];
    const float* theta  = (const float*)d_in[15];
    const float* aw     = (const float*)d_in[16];

    float* out = (float*)d_out;
    float* lp  = out + (size_t)NN * 64;

    char* w8 = (char*)d_ws;
    size_t off = 0;
    auto alloc = [&](size_t bytes) -> char* {
        char* p = w8 + off;
        off += (bytes + 255) / 256 * 256;
        return p;
    };
    // big region (NN*256 fp32 = 102.4 MB): h1 during gemm1->gemm2; then hl_tmp;
    // afterwards re-partitioned as h_bf / fpA_bf / fpB_bf / csr_wts.
    float* big     = (float*)alloc((size_t)NN * 256 * 4);
    float* h1      = big;
    float* hl_tmp  = big;
    short* h_bf    = (short*)big;
    short* fpA_bf  = (short*)big + (size_t)NN * 64;
    short* fpB_bf  = (short*)big + (size_t)NN * 64 * 2;
    float* csr_wts = (float*)((short*)big + (size_t)NN * 64 * 3);
    float* h      = (float*)alloc((size_t)NN * 64 * 4);
    float* hl     = (float*)alloc((size_t)NN * 64 * 4);
    float* ew     = (float*)alloc((size_t)EE * 4);   // ew in CSR order
    float* el     = (float*)alloc((size_t)NN * 4);
    float* er     = (float*)alloc((size_t)NN * 4);
    float* deg_s  = (float*)alloc((size_t)NN * 4);
    float* deg_d  = (float*)alloc((size_t)NN * 4);
    int*   cnt    = (int*)alloc((size_t)NN * 4);
    int*   row    = (int*)alloc((size_t)(NN + 1) * 4);
    int*   cur    = (int*)alloc((size_t)NN * 4);
    int*   csr_src= (int*)alloc((size_t)EE * 4);
    float* csr_w  = (float*)alloc((size_t)EE * 4);
    float* lp_part= (float*)alloc((size_t)100000 * 4);
    short* WT     = (short*)alloc((size_t)NHIDC * NFEATC * 2);

    hipMemsetAsync(cnt,   0, (size_t)NN * 4, stream);
    hipMemsetAsync(deg_s, 0, (size_t)NN * 4, stream);

    const int MB = (NN + 63) / 64;  // 1563

    // h1 = elu(x @ W_in)  -- bf16 MFMA path
    castWT_kernel<<<NFEATC, 256, 0, stream>>>(W_in, WT, NFEATC, NHIDC);
    gemm1_mfma_kernel<<<(NN + 127) / 128, 256, 0, stream>>>(x, WT, h1, NN);

    gemm_kernel<0><<<dim3(MB, 1), 256, 0, stream>>>(h1, W_out, nullptr, h, NN, NHIDC, NCC);
    gemm_kernel<1><<<dim3(MB, 1), 256, 0, stream>>>(latp, Ws1, b1, hl_tmp, NN, NCC, NCC);
    gemm_kernel<1><<<dim3(MB, 1), 256, 0, stream>>>(hl_tmp, Ws2, b2, hl, NN, NCC, NCC);
    // big is free (as h1/hl_tmp) after this point; CSR-era views take over.

    attn_kernel<<<NN / 4, 256, 0, stream>>>(h, attn_l, attn_r, el, er);
    count_kernel<<<EE / 256, 256, 0, stream>>>(dst, cnt);
    scan_kernel<<<1, 1024, 0, stream>>>(cnt, row, cur);
    bucket_kernel<<<EE / 256, 256, 0, stream>>>(src, dst, wts, cur, csr_src, csr_wts);

    // edge math in CSR order: dst side in registers, only src gathers random
    edge2_kernel<<<NN / 4, 256, 0, stream>>>(row, csr_src, csr_wts, h, hl, el, er,
                                             s_attn, beta, aw, ew, deg_s, deg_d, lp_part);
    reduce_kernel<<<1, 256, 0, stream>>>(lp_part, NN / 4, lp);

    wnorm_csr_kernel<<<NN / 16, 256, 0, stream>>>(row, csr_src, ew, deg_s, deg_d, theta, csr_w);

    // cast h -> bf16 gather source
    cast_bf_kernel<<<(NN * 64 / 4 + 255) / 256, 256, 0, stream>>>(h, h_bf, NN * 64 / 4);

    const short* fin = h_bf;
    short* bufs[2] = {fpA_bf, fpB_bf};
    for (int it = 0; it < 7; ++it) {
        short* fo = bufs[it & 1];
        prop_kernel<0><<<NN / 4, 256, 0, stream>>>(fin, h, row, csr_src, csr_w, fo, nullptr);
        fin = fo;
    }
    prop_kernel<1><<<NN / 4, 256, 0, stream>>>(fin, h, row, csr_src, csr_w, nullptr, out);
}

// Round 2
// 1321.658 us; speedup vs baseline: 1.3504x; 1.1606x over previous
//
#include <hip/hip_runtime.h>
#include <math.h>

#define NN 100000
#define EE 1600000
#define NFEATC 512
#define NHIDC 256
#define NCC 64
#define ALPHA_C 0.1f
#define NSLOPE_C 0.2f
#define SCAN_NB ((NN + 255) / 256)   // 391 blocks of 256 nodes

typedef __attribute__((ext_vector_type(8))) short short8;
typedef __attribute__((ext_vector_type(4))) short short4v;
typedef __attribute__((ext_vector_type(4))) float floatx4;

__device__ __forceinline__ short f2bf(float f) {
    unsigned u = __float_as_uint(f);
    unsigned r = (u + 0x7FFFu + ((u >> 16) & 1u)) >> 16;   // RNE
    return (short)r;
}
__device__ __forceinline__ float bf2f(short s) {
    return __uint_as_float(((unsigned)(unsigned short)s) << 16);
}

// ---------------- W_in transpose-cast: W[512][256] fp32 -> WT[256][512] bf16 ----------------
__global__ __launch_bounds__(256)
void castWT_kernel(const float* __restrict__ W, short* __restrict__ WT, int K, int Ncols)
{
    int k = blockIdx.x;
    int n = threadIdx.x;
    if (k < K && n < Ncols)
        WT[(size_t)n * K + k] = f2bf(W[(size_t)k * Ncols + n]);
}

// ---------------- elementwise fp32 -> bf16 cast (vectorized 4/thread) ----------------
__global__ __launch_bounds__(256)
void cast_bf_kernel(const float* __restrict__ in, short* __restrict__ out, int n4)
{
    int i = blockIdx.x * 256 + threadIdx.x;
    if (i >= n4) return;
    float4 v = reinterpret_cast<const float4*>(in)[i];
    short4v o;
    o[0] = f2bf(v.x); o[1] = f2bf(v.y); o[2] = f2bf(v.z); o[3] = f2bf(v.w);
    reinterpret_cast<short4v*>(out)[i] = o;
}

// ---------------- gemm1: h1 = elu(x @ W_in)  via bf16 MFMA ----------------
__global__ __launch_bounds__(256)
void gemm1_mfma_kernel(const float* __restrict__ x, const short* __restrict__ WT,
                       float* __restrict__ h1, int M)
{
    __shared__ short As[128][40];
    __shared__ short Bs[256][40];
    const int tid = threadIdx.x;
    const int bm = blockIdx.x * 128;
    const int wave = tid >> 6;
    const int lane = tid & 63;
    const int wm = wave >> 1;
    const int wn = wave & 1;
    const int l16 = lane & 15;
    const int quad = lane >> 4;

    floatx4 acc[4][8];
    #pragma unroll
    for (int i = 0; i < 4; ++i)
        #pragma unroll
        for (int j = 0; j < 8; ++j)
            acc[i][j] = (floatx4){0.f, 0.f, 0.f, 0.f};

    const int ar = tid >> 1;
    const int ah = tid & 1;
    const int xrow = bm + ar;
    const float* xp = x + (size_t)xrow * NFEATC + ah * 16;
    const short* wp = WT + (size_t)tid * NFEATC;

    for (int kt = 0; kt < NFEATC; kt += 32) {
        float4 a0, a1, a2, a3;
        if (xrow < M) {
            a0 = *reinterpret_cast<const float4*>(xp + kt + 0);
            a1 = *reinterpret_cast<const float4*>(xp + kt + 4);
            a2 = *reinterpret_cast<const float4*>(xp + kt + 8);
            a3 = *reinterpret_cast<const float4*>(xp + kt + 12);
        } else {
            a0 = a1 = a2 = a3 = make_float4(0.f, 0.f, 0.f, 0.f);
        }
        const short8* wq = reinterpret_cast<const short8*>(wp + kt);
        short8 b0 = wq[0], b1 = wq[1], b2 = wq[2], b3 = wq[3];

        short8 s0, s1;
        s0[0] = f2bf(a0.x); s0[1] = f2bf(a0.y); s0[2] = f2bf(a0.z); s0[3] = f2bf(a0.w);
        s0[4] = f2bf(a1.x); s0[5] = f2bf(a1.y); s0[6] = f2bf(a1.z); s0[7] = f2bf(a1.w);
        s1[0] = f2bf(a2.x); s1[1] = f2bf(a2.y); s1[2] = f2bf(a2.z); s1[3] = f2bf(a2.w);
        s1[4] = f2bf(a3.x); s1[5] = f2bf(a3.y); s1[6] = f2bf(a3.z); s1[7] = f2bf(a3.w);

        __syncthreads();
        *reinterpret_cast<short8*>(&As[ar][ah * 16 + 0]) = s0;
        *reinterpret_cast<short8*>(&As[ar][ah * 16 + 8]) = s1;
        *reinterpret_cast<short8*>(&Bs[tid][0])  = b0;
        *reinterpret_cast<short8*>(&Bs[tid][8])  = b1;
        *reinterpret_cast<short8*>(&Bs[tid][16]) = b2;
        *reinterpret_cast<short8*>(&Bs[tid][24]) = b3;
        __syncthreads();

        short8 af[4], bfr[8];
        #pragma unroll
        for (int mi = 0; mi < 4; ++mi)
            af[mi] = *reinterpret_cast<const short8*>(&As[wm * 64 + mi * 16 + l16][quad * 8]);
        #pragma unroll
        for (int ni = 0; ni < 8; ++ni)
            bfr[ni] = *reinterpret_cast<const short8*>(&Bs[wn * 128 + ni * 16 + l16][quad * 8]);
        #pragma unroll
        for (int mi = 0; mi < 4; ++mi)
            #pragma unroll
            for (int ni = 0; ni < 8; ++ni)
                acc[mi][ni] = __builtin_amdgcn_mfma_f32_16x16x32_bf16(af[mi], bfr[ni], acc[mi][ni], 0, 0, 0);
    }

    #pragma unroll
    for (int mi = 0; mi < 4; ++mi) {
        #pragma unroll
        for (int r = 0; r < 4; ++r) {
            int row = bm + wm * 64 + mi * 16 + quad * 4 + r;
            if (row >= M) continue;
            float* outp = h1 + (size_t)row * NHIDC + wn * 128 + l16;
            #pragma unroll
            for (int ni = 0; ni < 8; ++ni) {
                float v = acc[mi][ni][r];
                v = (v > 0.f) ? v : (expf(v) - 1.f);
                outp[ni * 16] = v;
            }
        }
    }
}

// ---------------- GEMM: C = act(A@B + bias), tile 64x64, KT=16, 256 thr, 4x4 micro ----------------
template<int ACT>
__global__ __launch_bounds__(256)
void gemm_kernel(const float* __restrict__ A, const float* __restrict__ B,
                 const float* __restrict__ bias, float* __restrict__ C,
                 int M, int K, int Ncols)
{
    __shared__ float As[16][68];
    __shared__ float Bs[16][64];
    const int tid = threadIdx.x;
    const int bm = blockIdx.x * 64;
    const int bn = blockIdx.y * 64;
    const int m0 = (tid & 15) * 4;
    const int n0 = (tid >> 4) * 4;
    float acc[4][4] = {};

    const int am = bm + (tid >> 2);
    const int ak = (tid & 3) * 4;
    const int bk = tid >> 4;
    const int bn4 = bn + (tid & 15) * 4;

    for (int kt = 0; kt < K; kt += 16) {
        float4 av;
        if (am < M) av = *reinterpret_cast<const float4*>(A + (size_t)am * K + kt + ak);
        else        av = make_float4(0.f, 0.f, 0.f, 0.f);
        float4 bv = *reinterpret_cast<const float4*>(B + (size_t)(kt + bk) * Ncols + bn4);
        __syncthreads();
        As[ak + 0][tid >> 2] = av.x;
        As[ak + 1][tid >> 2] = av.y;
        As[ak + 2][tid >> 2] = av.z;
        As[ak + 3][tid >> 2] = av.w;
        *reinterpret_cast<float4*>(&Bs[bk][(tid & 15) * 4]) = bv;
        __syncthreads();
        #pragma unroll
        for (int k = 0; k < 16; ++k) {
            float4 a4 = *reinterpret_cast<const float4*>(&As[k][m0]);
            float4 b4 = *reinterpret_cast<const float4*>(&Bs[k][n0]);
            float a_[4] = {a4.x, a4.y, a4.z, a4.w};
            float b_[4] = {b4.x, b4.y, b4.z, b4.w};
            #pragma unroll
            for (int i = 0; i < 4; ++i)
                #pragma unroll
                for (int j = 0; j < 4; ++j)
                    acc[i][j] = fmaf(a_[i], b_[j], acc[i][j]);
        }
    }

    float bvals[4] = {0.f, 0.f, 0.f, 0.f};
    if (bias) {
        bvals[0] = bias[bn + n0 + 0]; bvals[1] = bias[bn + n0 + 1];
        bvals[2] = bias[bn + n0 + 2]; bvals[3] = bias[bn + n0 + 3];
    }
    #pragma unroll
    for (int i = 0; i < 4; ++i) {
        int r = bm + m0 + i;
        if (r >= M) break;
        float v[4];
        #pragma unroll
        for (int j = 0; j < 4; ++j) {
            float t = acc[i][j] + bvals[j];
            if (ACT == 1) t = (t > 0.f) ? t : (expf(t) - 1.f);
            v[j] = t;
        }
        float4 o = make_float4(v[0], v[1], v[2], v[3]);
        *reinterpret_cast<float4*>(C + (size_t)r * Ncols + bn + n0) = o;
    }
}

// ---------------- per-node attention scalars: el, er ----------------
__global__ __launch_bounds__(256)
void attn_kernel(const float* __restrict__ h, const float* __restrict__ attn_l,
                 const float* __restrict__ attn_r, float* __restrict__ el, float* __restrict__ er)
{
    int node = blockIdx.x * 4 + (threadIdx.x >> 6);
    int lane = threadIdx.x & 63;
    if (node >= NN) return;
    float v = h[(size_t)node * 64 + lane];
    float lr = (v > 0.f) ? v : NSLOPE_C * v;
    float a = lr * attn_l[lane];
    float b = lr * attn_r[lane];
    #pragma unroll
    for (int m = 1; m < 64; m <<= 1) {
        a += __shfl_xor(a, m);
        b += __shfl_xor(b, m);
    }
    if (lane == 0) { el[node] = a; er[node] = b; }
}

// ---------------- CSR build ----------------
__global__ __launch_bounds__(256)
void count_kernel(const int* __restrict__ dst, int* __restrict__ cnt)
{
    int e = blockIdx.x * 256 + threadIdx.x;
    if (e < EE) atomicAdd(cnt + dst[e], 1);
}

// ---- 3-phase parallel exclusive scan over cnt[NN] -> row[], cur[] ----
// phase 1: per-block (256 nodes) sum -> partials[SCAN_NB]
__global__ __launch_bounds__(256)
void scan1_kernel(const int* __restrict__ cnt, int* __restrict__ partials)
{
    int i = blockIdx.x * 256 + threadIdx.x;
    int v = (i < NN) ? cnt[i] : 0;
    #pragma unroll
    for (int m = 1; m < 64; m <<= 1) v += __shfl_xor(v, m);
    __shared__ int sred[4];
    if ((threadIdx.x & 63) == 0) sred[threadIdx.x >> 6] = v;
    __syncthreads();
    if (threadIdx.x == 0)
        partials[blockIdx.x] = sred[0] + sred[1] + sred[2] + sred[3];
}

// phase 2: single-block exclusive scan over partials (SCAN_NB <= 512)
__global__ __launch_bounds__(512)
void scan2_kernel(int* __restrict__ partials)
{
    __shared__ int s[512];
    int t = threadIdx.x;
    int v = (t < SCAN_NB) ? partials[t] : 0;
    s[t] = v;
    __syncthreads();
    #pragma unroll
    for (int off = 1; off < 512; off <<= 1) {
        int add = (t >= off) ? s[t - off] : 0;
        __syncthreads();
        s[t] += add;
        __syncthreads();
    }
    if (t < SCAN_NB) partials[t] = s[t] - v;   // exclusive
}

// phase 3: per-block exclusive scan + offset; writes row[], cur[], row[NN]
__global__ __launch_bounds__(256)
void scan3_kernel(const int* __restrict__ cnt, const int* __restrict__ partials,
                  int* __restrict__ row, int* __restrict__ cur)
{
    __shared__ int s[256];
    int t = threadIdx.x;
    int i = blockIdx.x * 256 + t;
    int v = (i < NN) ? cnt[i] : 0;
    s[t] = v;
    __syncthreads();
    #pragma unroll
    for (int off = 1; off < 256; off <<= 1) {
        int add = (t >= off) ? s[t - off] : 0;
        __syncthreads();
        s[t] += add;
        __syncthreads();
    }
    int r = partials[blockIdx.x] + s[t] - v;   // exclusive prefix
    if (i < NN) { row[i] = r; cur[i] = r; }
    if (i == NN - 1) row[NN] = r + v;
}

// bucket: scatter src index + original edge weight into CSR order (by dst)
__global__ __launch_bounds__(256)
void bucket_kernel(const int* __restrict__ src, const int* __restrict__ dst,
                   const float* __restrict__ wts, int* __restrict__ cur,
                   int* __restrict__ csr_src, float* __restrict__ csr_wts)
{
    int e = blockIdx.x * 256 + threadIdx.x;
    if (e >= EE) return;
    int d = dst[e];
    int pos = atomicAdd(cur + d, 1);
    csr_src[pos] = src[e];
    csr_wts[pos] = wts[e];
}

// ---------------- edge computation in CSR (dst-grouped) order ----------------
__global__ __launch_bounds__(256)
void edge2_kernel(const int* __restrict__ row, const int* __restrict__ csr_src,
                  const float* __restrict__ csr_wts,
                  const float* __restrict__ h, const float* __restrict__ hl,
                  const float* __restrict__ el, const float* __restrict__ er,
                  const float* __restrict__ s_attn, const float* __restrict__ beta,
                  const float* __restrict__ aw,
                  float* __restrict__ ew, float* __restrict__ deg_s,
                  float* __restrict__ deg_d, float* __restrict__ lp_part)
{
    int node = blockIdx.x * 4 + (threadIdx.x >> 6);
    int lane = threadIdx.x & 63;
    int sub = lane >> 4;      // 4 edges in flight per wave
    int f = lane & 15;        // 16 lanes x float4 = full 64-feature row
    float lp_p = 0.f;
    if (node < NN) {
        int b = row[node], en = row[node + 1];
        const float4 hd = *reinterpret_cast<const float4*>(h  + (size_t)node * 64 + f * 4);
        const float4 ld = *reinterpret_cast<const float4*>(hl + (size_t)node * 64 + f * 4);
        const float4 sa = *reinterpret_cast<const float4*>(s_attn + f * 4);
        float erd = er[node];
        float betaw = 2.f / (expf(-beta[0]) + 1.f);
        float a0 = aw[0], a1 = aw[1];
        float mxw = fmaxf(a0, a1);
        float e0 = expf(a0 - mxw), e1 = expf(a1 - mxw);
        float inv = 1.f / (e0 + e1);
        float w0 = e0 * inv, w1 = e1 * inv;
        float degd = 0.f;
        for (int e = b + sub; e < en; e += 4) {
            int s = csr_src[e];
            const float4 hs = *reinterpret_cast<const float4*>(h  + (size_t)s * 64 + f * 4);
            const float4 ls = *reinterpret_cast<const float4*>(hl + (size_t)s * 64 + f * 4);
            float se_p  = ls.x * sa.x * ld.x + ls.y * sa.y * ld.y
                        + ls.z * sa.z * ld.z + ls.w * sa.w * ld.w;
            float dot_p = ls.x * ld.x + ls.y * ld.y + ls.z * ld.z + ls.w * ld.w;
            float dx = hs.x - hd.x, dy = hs.y - hd.y, dz = hs.z - hd.z, dw = hs.w - hd.w;
            float sdf_p = dx * dx + dy * dy + dz * dz + dw * dw;
            float ex = ls.x - ld.x, ey = ls.y - ld.y, ez = ls.z - ld.z, ec = ls.w - ld.w;
            float sds_p = ex * ex + ey * ey + ez * ez + ec * ec;
            #pragma unroll
            for (int m = 1; m < 16; m <<= 1) {
                se_p  += __shfl_xor(se_p, m);
                dot_p += __shfl_xor(dot_p, m);
                sdf_p += __shfl_xor(sdf_p, m);
                sds_p += __shfl_xor(sds_p, m);
            }
            if (f == 0) {
                float evv = el[s] + erd + se_p;
                float dd = w0 * sdf_p + w1 * sds_p;
                float v = expf(evv - betaw * dd) + 1e-9f;
                ew[e] = v;
                atomicAdd(deg_s + s, v);
                degd += v;
                lp_p += dot_p * csr_wts[e];
            }
        }
        #pragma unroll
        for (int m = 16; m < 64; m <<= 1) degd += __shfl_xor(degd, m);
        if (lane == 0) deg_d[node] = degd;
    }
    // lp block reduction (lp_p nonzero only on f==0 lanes)
    #pragma unroll
    for (int m = 16; m < 64; m <<= 1) lp_p += __shfl_xor(lp_p, m);
    __shared__ float lred[4];
    if ((threadIdx.x & 63) == 0) lred[threadIdx.x >> 6] = lp_p;
    __syncthreads();
    if (threadIdx.x == 0) lp_part[blockIdx.x] = lred[0] + lred[1] + lred[2] + lred[3];
}

// ---------------- reduce lp partials ----------------
__global__ __launch_bounds__(256)
void reduce_kernel(const float* __restrict__ part, int n, float* __restrict__ out)
{
    float s = 0.f;
    for (int i = threadIdx.x; i < n; i += 256) s += part[i];
    #pragma unroll
    for (int m = 1; m < 64; m <<= 1) s += __shfl_xor(s, m);
    __shared__ float sd[4];
    if ((threadIdx.x & 63) == 0) sd[threadIdx.x >> 6] = s;
    __syncthreads();
    if (threadIdx.x == 0) out[0] = sd[0] + sd[1] + sd[2] + sd[3];
}

// ---------------- edge normalization, CSR order (sequential) ----------------
__global__ __launch_bounds__(256)
void wnorm_csr_kernel(const int* __restrict__ row, const int* __restrict__ csr_src,
                      const float* __restrict__ ew, const float* __restrict__ deg_s,
                      const float* __restrict__ deg_d, const float* __restrict__ theta,
                      float* __restrict__ csr_w)
{
    int node = blockIdx.x * 16 + (threadIdx.x >> 4);
    int f = threadIdx.x & 15;
    if (node >= NN) return;
    int b = row[node], en = row[node + 1];
    float perm = 1e-9f / (expf(-theta[0]) + 1.f);
    float dr = rsqrtf(deg_d[node]);
    for (int e = b + f; e < en; e += 16) {
        float v = ew[e] * rsqrtf(deg_s[csr_src[e]]) * dr + perm;
        csr_w[e] = (1.0f - ALPHA_C) * v;
    }
}

// ---------------- propagation (bf16 gather, fp32 accumulate) ----------------
template<int FINAL>
__global__ __launch_bounds__(256)
void prop_kernel(const short* __restrict__ fin, const float* __restrict__ h,
                 const int* __restrict__ row, const int* __restrict__ csr_src,
                 const float* __restrict__ csr_w,
                 short* __restrict__ foutb, float* __restrict__ outf)
{
    int node = blockIdx.x * 4 + (threadIdx.x >> 6);
    int lane = threadIdx.x & 63;
    int sub = lane >> 3;   // 8 edges in flight
    int f = lane & 7;      // 8 features per lane
    if (node >= NN) return;
    int b = row[node], en = row[node + 1];
    float acc[8] = {};
    for (int e = b + sub; e < en; e += 8) {
        int s = csr_src[e];
        float wv = csr_w[e];
        short8 v = *reinterpret_cast<const short8*>(fin + (size_t)s * 64 + f * 8);
        #pragma unroll
        for (int i = 0; i < 8; ++i)
            acc[i] = fmaf(wv, bf2f(v[i]), acc[i]);
    }
    #pragma unroll
    for (int m = 8; m < 64; m <<= 1)
        #pragma unroll
        for (int i = 0; i < 8; ++i)
            acc[i] += __shfl_xor(acc[i], m);
    if (sub == 0) {
        const float4 h0 = *reinterpret_cast<const float4*>(h + (size_t)node * 64 + f * 8 + 0);
        const float4 h1v = *reinterpret_cast<const float4*>(h + (size_t)node * 64 + f * 8 + 4);
        float o[8];
        o[0] = fmaf(ALPHA_C, h0.x, acc[0]);
        o[1] = fmaf(ALPHA_C, h0.y, acc[1]);
        o[2] = fmaf(ALPHA_C, h0.z, acc[2]);
        o[3] = fmaf(ALPHA_C, h0.w, acc[3]);
        o[4] = fmaf(ALPHA_C, h1v.x, acc[4]);
        o[5] = fmaf(ALPHA_C, h1v.y, acc[5]);
        o[6] = fmaf(ALPHA_C, h1v.z, acc[6]);
        o[7] = fmaf(ALPHA_C, h1v.w, acc[7]);
        if (!FINAL) {
            short8 ob;
            #pragma unroll
            for (int i = 0; i < 8; ++i) ob[i] = f2bf(o[i]);
            *reinterpret_cast<short8*>(foutb + (size_t)node * 64 + f * 8) = ob;
        } else {
            float ev[8];
            #pragma unroll
            for (int i = 0; i < 8; ++i)
                ev[i] = (o[i] > 0.f) ? o[i] : (expf(o[i]) - 1.f);
            float mx = ev[0];
            #pragma unroll
            for (int i = 1; i < 8; ++i) mx = fmaxf(mx, ev[i]);
            #pragma unroll
            for (int m = 1; m < 8; m <<= 1) mx = fmaxf(mx, __shfl_xor(mx, m));
            float s = 0.f;
            #pragma unroll
            for (int i = 0; i < 8; ++i) s += expf(ev[i] - mx);
            #pragma unroll
            for (int m = 1; m < 8; m <<= 1) s += __shfl_xor(s, m);
            float ls = mx + logf(s);
            float4 o0 = make_float4(ev[0] - ls, ev[1] - ls, ev[2] - ls, ev[3] - ls);
            float4 o1 = make_float4(ev[4] - ls, ev[5] - ls, ev[6] - ls, ev[7] - ls);
            *reinterpret_cast<float4*>(outf + (size_t)node * 64 + f * 8 + 0) = o0;
            *reinterpret_cast<float4*>(outf + (size_t)node * 64 + f * 8 + 4) = o1;
        }
    }
}

extern "C" void kernel_launch(void* const* d_in, const int* in_sizes, int n_in,
                              void* d_out, int out_size, void* d_ws, size_t ws_size,
                              hipStream_t stream)
{
    const float* x      = (const float*)d_in[0];
    const int*   src    = (const int*)d_in[1];
    const int*   dst    = (const int*)d_in[2];
    const float* wts    = (const float*)d_in[3];
    const float* latp   = (const float*)d_in[4];
    const float* W_in   = (const float*)d_in[5];
    const float* W_out  = (const float*)d_in[6];
    const float* Ws1    = (const float*)d_in[7];
    const float* b1     = (const float*)d_in[8];
    const float* Ws2    = (const float*)d_in[9];
    const float* b2     = (const float*)d_in[10];
    const float* attn_l = (const float*)d_in[11];
    const float* attn_r = (const float*)d_in[12];
    const float* s_attn = (const float*)d_in[13];
    const float* beta   = (const float*)d_in[14];
    const float* theta  = (const float*)d_in[15];
    const float* aw     = (const float*)d_in[16];

    float* out = (float*)d_out;
    float* lp  = out + (size_t)NN * 64;

    char* w8 = (char*)d_ws;
    size_t off = 0;
    auto alloc = [&](size_t bytes) -> char* {
        char* p = w8 + off;
        off += (bytes + 255) / 256 * 256;
        return p;
    };
    float* big     = (float*)alloc((size_t)NN * 256 * 4);
    float* h1      = big;
    float* hl_tmp  = big;
    short* h_bf    = (short*)big;
    short* fpA_bf  = (short*)big + (size_t)NN * 64;
    short* fpB_bf  = (short*)big + (size_t)NN * 64 * 2;
    float* csr_wts = (float*)((short*)big + (size_t)NN * 64 * 3);
    float* h      = (float*)alloc((size_t)NN * 64 * 4);
    float* hl     = (float*)alloc((size_t)NN * 64 * 4);
    float* ew     = (float*)alloc((size_t)EE * 4);   // ew in CSR order
    float* el     = (float*)alloc((size_t)NN * 4);
    float* er     = (float*)alloc((size_t)NN * 4);
    float* deg_s  = (float*)alloc((size_t)NN * 4);
    float* deg_d  = (float*)alloc((size_t)NN * 4);
    int*   cnt    = (int*)alloc((size_t)NN * 4);
    int*   row    = (int*)alloc((size_t)(NN + 1) * 4);
    int*   cur    = (int*)alloc((size_t)NN * 4);
    int*   csr_src= (int*)alloc((size_t)EE * 4);
    float* csr_w  = (float*)alloc((size_t)EE * 4);
    float* lp_part= (float*)alloc((size_t)100000 * 4);
    int*   partials=(int*)alloc((size_t)SCAN_NB * 4);
    short* WT     = (short*)alloc((size_t)NHIDC * NFEATC * 2);

    hipMemsetAsync(cnt,   0, (size_t)NN * 4, stream);
    hipMemsetAsync(deg_s, 0, (size_t)NN * 4, stream);

    const int MB = (NN + 63) / 64;  // 1563

    // h1 = elu(x @ W_in)  -- bf16 MFMA path
    castWT_kernel<<<NFEATC, 256, 0, stream>>>(W_in, WT, NFEATC, NHIDC);
    gemm1_mfma_kernel<<<(NN + 127) / 128, 256, 0, stream>>>(x, WT, h1, NN);

    gemm_kernel<0><<<dim3(MB, 1), 256, 0, stream>>>(h1, W_out, nullptr, h, NN, NHIDC, NCC);
    gemm_kernel<1><<<dim3(MB, 1), 256, 0, stream>>>(latp, Ws1, b1, hl_tmp, NN, NCC, NCC);
    gemm_kernel<1><<<dim3(MB, 1), 256, 0, stream>>>(hl_tmp, Ws2, b2, hl, NN, NCC, NCC);

    attn_kernel<<<NN / 4, 256, 0, stream>>>(h, attn_l, attn_r, el, er);
    count_kernel<<<EE / 256, 256, 0, stream>>>(dst, cnt);
    scan1_kernel<<<SCAN_NB, 256, 0, stream>>>(cnt, partials);
    scan2_kernel<<<1, 512, 0, stream>>>(partials);
    scan3_kernel<<<SCAN_NB, 256, 0, stream>>>(cnt, partials, row, cur);
    bucket_kernel<<<EE / 256, 256, 0, stream>>>(src, dst, wts, cur, csr_src, csr_wts);

    // edge math in CSR order: dst side in registers, only src gathers random
    edge2_kernel<<<NN / 4, 256, 0, stream>>>(row, csr_src, csr_wts, h, hl, el, er,
                                             s_attn, beta, aw, ew, deg_s, deg_d, lp_part);
    reduce_kernel<<<1, 256, 0, stream>>>(lp_part, NN / 4, lp);

    wnorm_csr_kernel<<<NN / 16, 256, 0, stream>>>(row, csr_src, ew, deg_s, deg_d, theta, csr_w);

    // cast h -> bf16 gather source
    cast_bf_kernel<<<(NN * 64 / 4 + 255) / 256, 256, 0, stream>>>(h, h_bf, NN * 64 / 4);

    const short* fin = h_bf;
    short* bufs[2] = {fpA_bf, fpB_bf};
    for (int it = 0; it < 7; ++it) {
        short* fo = bufs[it & 1];
        prop_kernel<0><<<NN / 4, 256, 0, stream>>>(fin, h, row, csr_src, csr_w, fo, nullptr);
        fin = fo;
    }
    prop_kernel<1><<<NN / 4, 256, 0, stream>>>(fin, h, row, csr_src, csr_w, nullptr, out);
}

// Round 3
// 1256.678 us; speedup vs baseline: 1.4202x; 1.0517x over previous
//
#include <hip/hip_runtime.h>
#include <math.h>

#define NN 100000
#define EE 1600000
#define NFEATC 512
#define NHIDC 256
#define NCC 64
#define ALPHA_C 0.1f
#define NSLOPE_C 0.2f
#define SCAN_NB ((NN + 255) / 256)   // 391 blocks of 256 nodes

typedef __attribute__((ext_vector_type(8))) short short8;
typedef __attribute__((ext_vector_type(4))) short short4v;
typedef __attribute__((ext_vector_type(4))) float floatx4;

__device__ __forceinline__ short f2bf(float f) {
    unsigned u = __float_as_uint(f);
    unsigned r = (u + 0x7FFFu + ((u >> 16) & 1u)) >> 16;   // RNE
    return (short)r;
}
__device__ __forceinline__ float bf2f(short s) {
    return __uint_as_float(((unsigned)(unsigned short)s) << 16);
}

// ---------------- W_in transpose-cast: W[512][256] fp32 -> WT[256][512] bf16 ----------------
__global__ __launch_bounds__(256)
void castWT_kernel(const float* __restrict__ W, short* __restrict__ WT, int K, int Ncols)
{
    int k = blockIdx.x;
    int n = threadIdx.x;
    if (k < K && n < Ncols)
        WT[(size_t)n * K + k] = f2bf(W[(size_t)k * Ncols + n]);
}

// ---------------- elementwise fp32 -> bf16 cast (vectorized 4/thread) ----------------
__global__ __launch_bounds__(256)
void cast_bf_kernel(const float* __restrict__ in, short* __restrict__ out, int n4)
{
    int i = blockIdx.x * 256 + threadIdx.x;
    if (i >= n4) return;
    float4 v = reinterpret_cast<const float4*>(in)[i];
    short4v o;
    o[0] = f2bf(v.x); o[1] = f2bf(v.y); o[2] = f2bf(v.z); o[3] = f2bf(v.w);
    reinterpret_cast<short4v*>(out)[i] = o;
}

// ---------------- gemm1: h1 = elu(x @ W_in)  via bf16 MFMA ----------------
__global__ __launch_bounds__(256)
void gemm1_mfma_kernel(const float* __restrict__ x, const short* __restrict__ WT,
                       float* __restrict__ h1, int M)
{
    __shared__ short As[128][40];
    __shared__ short Bs[256][40];
    const int tid = threadIdx.x;
    const int bm = blockIdx.x * 128;
    const int wave = tid >> 6;
    const int lane = tid & 63;
    const int wm = wave >> 1;
    const int wn = wave & 1;
    const int l16 = lane & 15;
    const int quad = lane >> 4;

    floatx4 acc[4][8];
    #pragma unroll
    for (int i = 0; i < 4; ++i)
        #pragma unroll
        for (int j = 0; j < 8; ++j)
            acc[i][j] = (floatx4){0.f, 0.f, 0.f, 0.f};

    const int ar = tid >> 1;
    const int ah = tid & 1;
    const int xrow = bm + ar;
    const float* xp = x + (size_t)xrow * NFEATC + ah * 16;
    const short* wp = WT + (size_t)tid * NFEATC;

    for (int kt = 0; kt < NFEATC; kt += 32) {
        float4 a0, a1, a2, a3;
        if (xrow < M) {
            a0 = *reinterpret_cast<const float4*>(xp + kt + 0);
            a1 = *reinterpret_cast<const float4*>(xp + kt + 4);
            a2 = *reinterpret_cast<const float4*>(xp + kt + 8);
            a3 = *reinterpret_cast<const float4*>(xp + kt + 12);
        } else {
            a0 = a1 = a2 = a3 = make_float4(0.f, 0.f, 0.f, 0.f);
        }
        const short8* wq = reinterpret_cast<const short8*>(wp + kt);
        short8 b0 = wq[0], b1 = wq[1], b2 = wq[2], b3 = wq[3];

        short8 s0, s1;
        s0[0] = f2bf(a0.x); s0[1] = f2bf(a0.y); s0[2] = f2bf(a0.z); s0[3] = f2bf(a0.w);
        s0[4] = f2bf(a1.x); s0[5] = f2bf(a1.y); s0[6] = f2bf(a1.z); s0[7] = f2bf(a1.w);
        s1[0] = f2bf(a2.x); s1[1] = f2bf(a2.y); s1[2] = f2bf(a2.z); s1[3] = f2bf(a2.w);
        s1[4] = f2bf(a3.x); s1[5] = f2bf(a3.y); s1[6] = f2bf(a3.z); s1[7] = f2bf(a3.w);

        __syncthreads();
        *reinterpret_cast<short8*>(&As[ar][ah * 16 + 0]) = s0;
        *reinterpret_cast<short8*>(&As[ar][ah * 16 + 8]) = s1;
        *reinterpret_cast<short8*>(&Bs[tid][0])  = b0;
        *reinterpret_cast<short8*>(&Bs[tid][8])  = b1;
        *reinterpret_cast<short8*>(&Bs[tid][16]) = b2;
        *reinterpret_cast<short8*>(&Bs[tid][24]) = b3;
        __syncthreads();

        short8 af[4], bfr[8];
        #pragma unroll
        for (int mi = 0; mi < 4; ++mi)
            af[mi] = *reinterpret_cast<const short8*>(&As[wm * 64 + mi * 16 + l16][quad * 8]);
        #pragma unroll
        for (int ni = 0; ni < 8; ++ni)
            bfr[ni] = *reinterpret_cast<const short8*>(&Bs[wn * 128 + ni * 16 + l16][quad * 8]);
        #pragma unroll
        for (int mi = 0; mi < 4; ++mi)
            #pragma unroll
            for (int ni = 0; ni < 8; ++ni)
                acc[mi][ni] = __builtin_amdgcn_mfma_f32_16x16x32_bf16(af[mi], bfr[ni], acc[mi][ni], 0, 0, 0);
    }

    #pragma unroll
    for (int mi = 0; mi < 4; ++mi) {
        #pragma unroll
        for (int r = 0; r < 4; ++r) {
            int row = bm + wm * 64 + mi * 16 + quad * 4 + r;
            if (row >= M) continue;
            float* outp = h1 + (size_t)row * NHIDC + wn * 128 + l16;
            #pragma unroll
            for (int ni = 0; ni < 8; ++ni) {
                float v = acc[mi][ni][r];
                v = (v > 0.f) ? v : (expf(v) - 1.f);
                outp[ni * 16] = v;
            }
        }
    }
}

// ---------------- GEMM: C = act(A@B + bias), tile 64x64, KT=16, 256 thr, 4x4 micro ----------------
template<int ACT>
__global__ __launch_bounds__(256)
void gemm_kernel(const float* __restrict__ A, const float* __restrict__ B,
                 const float* __restrict__ bias, float* __restrict__ C,
                 int M, int K, int Ncols)
{
    __shared__ float As[16][68];
    __shared__ float Bs[16][64];
    const int tid = threadIdx.x;
    const int bm = blockIdx.x * 64;
    const int bn = blockIdx.y * 64;
    const int m0 = (tid & 15) * 4;
    const int n0 = (tid >> 4) * 4;
    float acc[4][4] = {};

    const int am = bm + (tid >> 2);
    const int ak = (tid & 3) * 4;
    const int bk = tid >> 4;
    const int bn4 = bn + (tid & 15) * 4;

    for (int kt = 0; kt < K; kt += 16) {
        float4 av;
        if (am < M) av = *reinterpret_cast<const float4*>(A + (size_t)am * K + kt + ak);
        else        av = make_float4(0.f, 0.f, 0.f, 0.f);
        float4 bv = *reinterpret_cast<const float4*>(B + (size_t)(kt + bk) * Ncols + bn4);
        __syncthreads();
        As[ak + 0][tid >> 2] = av.x;
        As[ak + 1][tid >> 2] = av.y;
        As[ak + 2][tid >> 2] = av.z;
        As[ak + 3][tid >> 2] = av.w;
        *reinterpret_cast<float4*>(&Bs[bk][(tid & 15) * 4]) = bv;
        __syncthreads();
        #pragma unroll
        for (int k = 0; k < 16; ++k) {
            float4 a4 = *reinterpret_cast<const float4*>(&As[k][m0]);
            float4 b4 = *reinterpret_cast<const float4*>(&Bs[k][n0]);
            float a_[4] = {a4.x, a4.y, a4.z, a4.w};
            float b_[4] = {b4.x, b4.y, b4.z, b4.w};
            #pragma unroll
            for (int i = 0; i < 4; ++i)
                #pragma unroll
                for (int j = 0; j < 4; ++j)
                    acc[i][j] = fmaf(a_[i], b_[j], acc[i][j]);
        }
    }

    float bvals[4] = {0.f, 0.f, 0.f, 0.f};
    if (bias) {
        bvals[0] = bias[bn + n0 + 0]; bvals[1] = bias[bn + n0 + 1];
        bvals[2] = bias[bn + n0 + 2]; bvals[3] = bias[bn + n0 + 3];
    }
    #pragma unroll
    for (int i = 0; i < 4; ++i) {
        int r = bm + m0 + i;
        if (r >= M) break;
        float v[4];
        #pragma unroll
        for (int j = 0; j < 4; ++j) {
            float t = acc[i][j] + bvals[j];
            if (ACT == 1) t = (t > 0.f) ? t : (expf(t) - 1.f);
            v[j] = t;
        }
        float4 o = make_float4(v[0], v[1], v[2], v[3]);
        *reinterpret_cast<float4*>(C + (size_t)r * Ncols + bn + n0) = o;
    }
}

// ---------------- per-node scalars: A = el - bw(w0*nh+w1*nl), B = er - bw(w0*nh+w1*nl) ----------------
__global__ __launch_bounds__(256)
void attn2_kernel(const float* __restrict__ h, const float* __restrict__ hl,
                  const float* __restrict__ attn_l, const float* __restrict__ attn_r,
                  const float* __restrict__ beta, const float* __restrict__ aw,
                  float* __restrict__ A, float* __restrict__ B)
{
    int node = blockIdx.x * 4 + (threadIdx.x >> 6);
    int lane = threadIdx.x & 63;
    if (node >= NN) return;
    float v = h[(size_t)node * 64 + lane];
    float u = hl[(size_t)node * 64 + lane];
    float lr = (v > 0.f) ? v : NSLOPE_C * v;
    float a = lr * attn_l[lane];
    float b = lr * attn_r[lane];
    float nh = v * v;
    float nl = u * u;
    #pragma unroll
    for (int m = 1; m < 64; m <<= 1) {
        a += __shfl_xor(a, m);
        b += __shfl_xor(b, m);
        nh += __shfl_xor(nh, m);
        nl += __shfl_xor(nl, m);
    }
    if (lane == 0) {
        float betaw = 2.f / (expf(-beta[0]) + 1.f);
        float a0 = aw[0], a1 = aw[1];
        float mxw = fmaxf(a0, a1);
        float e0 = expf(a0 - mxw), e1 = expf(a1 - mxw);
        float inv = 1.f / (e0 + e1);
        float t = betaw * (e0 * inv * nh + e1 * inv * nl);
        A[node] = a - t;
        B[node] = b - t;
    }
}

// ---------------- CSR build ----------------
__global__ __launch_bounds__(256)
void count_kernel(const int* __restrict__ dst, int* __restrict__ cnt)
{
    int e = blockIdx.x * 256 + threadIdx.x;
    if (e < EE) atomicAdd(cnt + dst[e], 1);
}

// ---- 3-phase parallel exclusive scan over cnt[NN] -> row[], cur[] ----
__global__ __launch_bounds__(256)
void scan1_kernel(const int* __restrict__ cnt, int* __restrict__ partials)
{
    int i = blockIdx.x * 256 + threadIdx.x;
    int v = (i < NN) ? cnt[i] : 0;
    #pragma unroll
    for (int m = 1; m < 64; m <<= 1) v += __shfl_xor(v, m);
    __shared__ int sred[4];
    if ((threadIdx.x & 63) == 0) sred[threadIdx.x >> 6] = v;
    __syncthreads();
    if (threadIdx.x == 0)
        partials[blockIdx.x] = sred[0] + sred[1] + sred[2] + sred[3];
}

__global__ __launch_bounds__(512)
void scan2_kernel(int* __restrict__ partials)
{
    __shared__ int s[512];
    int t = threadIdx.x;
    int v = (t < SCAN_NB) ? partials[t] : 0;
    s[t] = v;
    __syncthreads();
    #pragma unroll
    for (int off = 1; off < 512; off <<= 1) {
        int add = (t >= off) ? s[t - off] : 0;
        __syncthreads();
        s[t] += add;
        __syncthreads();
    }
    if (t < SCAN_NB) partials[t] = s[t] - v;   // exclusive
}

__global__ __launch_bounds__(256)
void scan3_kernel(const int* __restrict__ cnt, const int* __restrict__ partials,
                  int* __restrict__ row, int* __restrict__ cur)
{
    __shared__ int s[256];
    int t = threadIdx.x;
    int i = blockIdx.x * 256 + t;
    int v = (i < NN) ? cnt[i] : 0;
    s[t] = v;
    __syncthreads();
    #pragma unroll
    for (int off = 1; off < 256; off <<= 1) {
        int add = (t >= off) ? s[t - off] : 0;
        __syncthreads();
        s[t] += add;
        __syncthreads();
    }
    int r = partials[blockIdx.x] + s[t] - v;   // exclusive prefix
    if (i < NN) { row[i] = r; cur[i] = r; }
    if (i == NN - 1) row[NN] = r + v;
}

// bucket: scatter src index + original edge weight into CSR order (by dst)
__global__ __launch_bounds__(256)
void bucket_kernel(const int* __restrict__ src, const int* __restrict__ dst,
                   const float* __restrict__ wts, int* __restrict__ cur,
                   int* __restrict__ csr_src, float* __restrict__ csr_wts)
{
    int e = blockIdx.x * 256 + threadIdx.x;
    if (e >= EE) return;
    int d = dst[e];
    int pos = atomicAdd(cur + d, 1);
    csr_src[pos] = src[e];
    csr_wts[pos] = wts[e];
}

// ---------------- edge computation, CSR order, norm-decomposed, 2x pipelined ----------------
// exponent = A[s] + B[d] + hs.P + ls.Q + c1*(ls.ld)
//   P = c0*hd, Q = sa(.)ld, c0 = 2*bw*w0, c1 = 2*bw*w1
__global__ __launch_bounds__(256)
void edge2_kernel(const int* __restrict__ row, const int* __restrict__ csr_src,
                  const float* __restrict__ csr_wts,
                  const float* __restrict__ h, const float* __restrict__ hl,
                  const float* __restrict__ A, const float* __restrict__ B,
                  const float* __restrict__ s_attn, const float* __restrict__ beta,
                  const float* __restrict__ aw,
                  float* __restrict__ ew, float* __restrict__ deg_s,
                  float* __restrict__ deg_d, float* __restrict__ lp_part)
{
    int node = blockIdx.x * 4 + (threadIdx.x >> 6);
    int lane = threadIdx.x & 63;
    int sub = lane >> 4;      // 4 edges in flight per wave (x2 unroll = 8)
    int f = lane & 15;        // 16 lanes x float4 = full 64-feature row
    float lp_p = 0.f;
    if (node < NN) {
        int b = row[node], en = row[node + 1];
        float betaw = 2.f / (expf(-beta[0]) + 1.f);
        float a0 = aw[0], a1 = aw[1];
        float mxw = fmaxf(a0, a1);
        float e0 = expf(a0 - mxw), e1 = expf(a1 - mxw);
        float inv = 1.f / (e0 + e1);
        float c0 = 2.f * betaw * e0 * inv;
        float c1 = 2.f * betaw * e1 * inv;
        const float4 hd = *reinterpret_cast<const float4*>(h  + (size_t)node * 64 + f * 4);
        const float4 ld = *reinterpret_cast<const float4*>(hl + (size_t)node * 64 + f * 4);
        const float4 sa = *reinterpret_cast<const float4*>(s_attn + f * 4);
        float4 P = make_float4(c0 * hd.x, c0 * hd.y, c0 * hd.z, c0 * hd.w);
        float4 Q = make_float4(sa.x * ld.x, sa.y * ld.y, sa.z * ld.z, sa.w * ld.w);
        float Bd = B[node];
        float degd = 0.f;
        int e = b + sub;
        for (; e + 4 < en; e += 8) {
            int s1 = csr_src[e];
            int s2 = csr_src[e + 4];
            const float4 hs1 = *reinterpret_cast<const float4*>(h  + (size_t)s1 * 64 + f * 4);
            const float4 ls1 = *reinterpret_cast<const float4*>(hl + (size_t)s1 * 64 + f * 4);
            const float4 hs2 = *reinterpret_cast<const float4*>(h  + (size_t)s2 * 64 + f * 4);
            const float4 ls2 = *reinterpret_cast<const float4*>(hl + (size_t)s2 * 64 + f * 4);
            float r1 = hs1.x * P.x + hs1.y * P.y + hs1.z * P.z + hs1.w * P.w
                     + ls1.x * Q.x + ls1.y * Q.y + ls1.z * Q.z + ls1.w * Q.w;
            float d31 = ls1.x * ld.x + ls1.y * ld.y + ls1.z * ld.z + ls1.w * ld.w;
            float r2 = hs2.x * P.x + hs2.y * P.y + hs2.z * P.z + hs2.w * P.w
                     + ls2.x * Q.x + ls2.y * Q.y + ls2.z * Q.z + ls2.w * Q.w;
            float d32 = ls2.x * ld.x + ls2.y * ld.y + ls2.z * ld.z + ls2.w * ld.w;
            #pragma unroll
            for (int m = 1; m < 16; m <<= 1) {
                r1  += __shfl_xor(r1, m);
                d31 += __shfl_xor(d31, m);
                r2  += __shfl_xor(r2, m);
                d32 += __shfl_xor(d32, m);
            }
            if (f == 0) {
                float v1 = expf(A[s1] + Bd + r1 + c1 * d31) + 1e-9f;
                ew[e] = v1;
                atomicAdd(deg_s + s1, v1);
                degd += v1;
                lp_p += d31 * csr_wts[e];
                float v2 = expf(A[s2] + Bd + r2 + c1 * d32) + 1e-9f;
                ew[e + 4] = v2;
                atomicAdd(deg_s + s2, v2);
                degd += v2;
                lp_p += d32 * csr_wts[e + 4];
            }
        }
        if (e < en) {
            int s1 = csr_src[e];
            const float4 hs1 = *reinterpret_cast<const float4*>(h  + (size_t)s1 * 64 + f * 4);
            const float4 ls1 = *reinterpret_cast<const float4*>(hl + (size_t)s1 * 64 + f * 4);
            float r1 = hs1.x * P.x + hs1.y * P.y + hs1.z * P.z + hs1.w * P.w
                     + ls1.x * Q.x + ls1.y * Q.y + ls1.z * Q.z + ls1.w * Q.w;
            float d31 = ls1.x * ld.x + ls1.y * ld.y + ls1.z * ld.z + ls1.w * ld.w;
            #pragma unroll
            for (int m = 1; m < 16; m <<= 1) {
                r1  += __shfl_xor(r1, m);
                d31 += __shfl_xor(d31, m);
            }
            if (f == 0) {
                float v1 = expf(A[s1] + Bd + r1 + c1 * d31) + 1e-9f;
                ew[e] = v1;
                atomicAdd(deg_s + s1, v1);
                degd += v1;
                lp_p += d31 * csr_wts[e];
            }
        }
        #pragma unroll
        for (int m = 16; m < 64; m <<= 1) degd += __shfl_xor(degd, m);
        if (lane == 0) deg_d[node] = degd;
    }
    // lp block reduction (lp_p nonzero only on f==0 lanes)
    #pragma unroll
    for (int m = 16; m < 64; m <<= 1) lp_p += __shfl_xor(lp_p, m);
    __shared__ float lred[4];
    if ((threadIdx.x & 63) == 0) lred[threadIdx.x >> 6] = lp_p;
    __syncthreads();
    if (threadIdx.x == 0) lp_part[blockIdx.x] = lred[0] + lred[1] + lred[2] + lred[3];
}

// ---------------- reduce lp partials ----------------
__global__ __launch_bounds__(256)
void reduce_kernel(const float* __restrict__ part, int n, float* __restrict__ out)
{
    float s = 0.f;
    for (int i = threadIdx.x; i < n; i += 256) s += part[i];
    #pragma unroll
    for (int m = 1; m < 64; m <<= 1) s += __shfl_xor(s, m);
    __shared__ float sd[4];
    if ((threadIdx.x & 63) == 0) sd[threadIdx.x >> 6] = s;
    __syncthreads();
    if (threadIdx.x == 0) out[0] = sd[0] + sd[1] + sd[2] + sd[3];
}

// ---------------- edge normalization, CSR order (sequential) ----------------
__global__ __launch_bounds__(256)
void wnorm_csr_kernel(const int* __restrict__ row, const int* __restrict__ csr_src,
                      const float* __restrict__ ew, const float* __restrict__ deg_s,
                      const float* __restrict__ deg_d, const float* __restrict__ theta,
                      float* __restrict__ csr_w)
{
    int node = blockIdx.x * 16 + (threadIdx.x >> 4);
    int f = threadIdx.x & 15;
    if (node >= NN) return;
    int b = row[node], en = row[node + 1];
    float perm = 1e-9f / (expf(-theta[0]) + 1.f);
    float dr = rsqrtf(deg_d[node]);
    for (int e = b + f; e < en; e += 16) {
        float v = ew[e] * rsqrtf(deg_s[csr_src[e]]) * dr + perm;
        csr_w[e] = (1.0f - ALPHA_C) * v;
    }
}

// ---------------- propagation (bf16 gather, fp32 accumulate, 2x pipelined) ----------------
template<int FINAL>
__global__ __launch_bounds__(256)
void prop_kernel(const short* __restrict__ fin, const float* __restrict__ h,
                 const int* __restrict__ row, const int* __restrict__ csr_src,
                 const float* __restrict__ csr_w,
                 short* __restrict__ foutb, float* __restrict__ outf)
{
    int node = blockIdx.x * 4 + (threadIdx.x >> 6);
    int lane = threadIdx.x & 63;
    int sub = lane >> 3;   // 8 edges in flight (x2 unroll = 16)
    int f = lane & 7;      // 8 features per lane
    if (node >= NN) return;
    int b = row[node], en = row[node + 1];
    float acc[8] = {};
    int e = b + sub;
    for (; e + 8 < en; e += 16) {
        int s1 = csr_src[e];
        float w1 = csr_w[e];
        int s2 = csr_src[e + 8];
        float w2 = csr_w[e + 8];
        short8 v1 = *reinterpret_cast<const short8*>(fin + (size_t)s1 * 64 + f * 8);
        short8 v2 = *reinterpret_cast<const short8*>(fin + (size_t)s2 * 64 + f * 8);
        #pragma unroll
        for (int i = 0; i < 8; ++i)
            acc[i] = fmaf(w1, bf2f(v1[i]), acc[i]);
        #pragma unroll
        for (int i = 0; i < 8; ++i)
            acc[i] = fmaf(w2, bf2f(v2[i]), acc[i]);
    }
    if (e < en) {
        int s1 = csr_src[e];
        float w1 = csr_w[e];
        short8 v1 = *reinterpret_cast<const short8*>(fin + (size_t)s1 * 64 + f * 8);
        #pragma unroll
        for (int i = 0; i < 8; ++i)
            acc[i] = fmaf(w1, bf2f(v1[i]), acc[i]);
    }
    #pragma unroll
    for (int m = 8; m < 64; m <<= 1)
        #pragma unroll
        for (int i = 0; i < 8; ++i)
            acc[i] += __shfl_xor(acc[i], m);
    if (sub == 0) {
        const float4 h0 = *reinterpret_cast<const float4*>(h + (size_t)node * 64 + f * 8 + 0);
        const float4 h1v = *reinterpret_cast<const float4*>(h + (size_t)node * 64 + f * 8 + 4);
        float o[8];
        o[0] = fmaf(ALPHA_C, h0.x, acc[0]);
        o[1] = fmaf(ALPHA_C, h0.y, acc[1]);
        o[2] = fmaf(ALPHA_C, h0.z, acc[2]);
        o[3] = fmaf(ALPHA_C, h0.w, acc[3]);
        o[4] = fmaf(ALPHA_C, h1v.x, acc[4]);
        o[5] = fmaf(ALPHA_C, h1v.y, acc[5]);
        o[6] = fmaf(ALPHA_C, h1v.z, acc[6]);
        o[7] = fmaf(ALPHA_C, h1v.w, acc[7]);
        if (!FINAL) {
            short8 ob;
            #pragma unroll
            for (int i = 0; i < 8; ++i) ob[i] = f2bf(o[i]);
            *reinterpret_cast<short8*>(foutb + (size_t)node * 64 + f * 8) = ob;
        } else {
            float ev[8];
            #pragma unroll
            for (int i = 0; i < 8; ++i)
                ev[i] = (o[i] > 0.f) ? o[i] : (expf(o[i]) - 1.f);
            float mx = ev[0];
            #pragma unroll
            for (int i = 1; i < 8; ++i) mx = fmaxf(mx, ev[i]);
            #pragma unroll
            for (int m = 1; m < 8; m <<= 1) mx = fmaxf(mx, __shfl_xor(mx, m));
            float s = 0.f;
            #pragma unroll
            for (int i = 0; i < 8; ++i) s += expf(ev[i] - mx);
            #pragma unroll
            for (int m = 1; m < 8; m <<= 1) s += __shfl_xor(s, m);
            float ls = mx + logf(s);
            float4 o0 = make_float4(ev[0] - ls, ev[1] - ls, ev[2] - ls, ev[3] - ls);
            float4 o1 = make_float4(ev[4] - ls, ev[5] - ls, ev[6] - ls, ev[7] - ls);
            *reinterpret_cast<float4*>(outf + (size_t)node * 64 + f * 8 + 0) = o0;
            *reinterpret_cast<float4*>(outf + (size_t)node * 64 + f * 8 + 4) = o1;
        }
    }
}

extern "C" void kernel_launch(void* const* d_in, const int* in_sizes, int n_in,
                              void* d_out, int out_size, void* d_ws, size_t ws_size,
                              hipStream_t stream)
{
    const float* x      = (const float*)d_in[0];
    const int*   src    = (const int*)d_in[1];
    const int*   dst    = (const int*)d_in[2];
    const float* wts    = (const float*)d_in[3];
    const float* latp   = (const float*)d_in[4];
    const float* W_in   = (const float*)d_in[5];
    const float* W_out  = (const float*)d_in[6];
    const float* Ws1    = (const float*)d_in[7];
    const float* b1     = (const float*)d_in[8];
    const float* Ws2    = (const float*)d_in[9];
    const float* b2     = (const float*)d_in[10];
    const float* attn_l = (const float*)d_in[11];
    const float* attn_r = (const float*)d_in[12];
    const float* s_attn = (const float*)d_in[13];
    const float* beta   = (const float*)d_in[14];
    const float* theta  = (const float*)d_in[15];
    const float* aw     = (const float*)d_in[16];

    float* out = (float*)d_out;
    float* lp  = out + (size_t)NN * 64;

    char* w8 = (char*)d_ws;
    size_t off = 0;
    auto alloc = [&](size_t bytes) -> char* {
        char* p = w8 + off;
        off += (bytes + 255) / 256 * 256;
        return p;
    };
    float* big     = (float*)alloc((size_t)NN * 256 * 4);
    float* h1      = big;
    float* hl_tmp  = big;
    short* h_bf    = (short*)big;
    short* fpA_bf  = (short*)big + (size_t)NN * 64;
    short* fpB_bf  = (short*)big + (size_t)NN * 64 * 2;
    float* csr_wts = (float*)((short*)big + (size_t)NN * 64 * 3);
    float* h      = (float*)alloc((size_t)NN * 64 * 4);
    float* hl     = (float*)alloc((size_t)NN * 64 * 4);
    float* ew     = (float*)alloc((size_t)EE * 4);   // ew in CSR order
    float* Aarr   = (float*)alloc((size_t)NN * 4);   // A = el - bw(w0 nh + w1 nl)
    float* Barr   = (float*)alloc((size_t)NN * 4);   // B = er - bw(w0 nh + w1 nl)
    float* deg_s  = (float*)alloc((size_t)NN * 4);
    float* deg_d  = (float*)alloc((size_t)NN * 4);
    int*   cnt    = (int*)alloc((size_t)NN * 4);
    int*   row    = (int*)alloc((size_t)(NN + 1) * 4);
    int*   cur    = (int*)alloc((size_t)NN * 4);
    int*   csr_src= (int*)alloc((size_t)EE * 4);
    float* csr_w  = (float*)alloc((size_t)EE * 4);
    float* lp_part= (float*)alloc((size_t)100000 * 4);
    int*   partials=(int*)alloc((size_t)SCAN_NB * 4);
    short* WT     = (short*)alloc((size_t)NHIDC * NFEATC * 2);

    hipMemsetAsync(cnt,   0, (size_t)NN * 4, stream);
    hipMemsetAsync(deg_s, 0, (size_t)NN * 4, stream);

    const int MB = (NN + 63) / 64;  // 1563

    // h1 = elu(x @ W_in)  -- bf16 MFMA path
    castWT_kernel<<<NFEATC, 256, 0, stream>>>(W_in, WT, NFEATC, NHIDC);
    gemm1_mfma_kernel<<<(NN + 127) / 128, 256, 0, stream>>>(x, WT, h1, NN);

    gemm_kernel<0><<<dim3(MB, 1), 256, 0, stream>>>(h1, W_out, nullptr, h, NN, NHIDC, NCC);
    gemm_kernel<1><<<dim3(MB, 1), 256, 0, stream>>>(latp, Ws1, b1, hl_tmp, NN, NCC, NCC);
    gemm_kernel<1><<<dim3(MB, 1), 256, 0, stream>>>(hl_tmp, Ws2, b2, hl, NN, NCC, NCC);

    attn2_kernel<<<NN / 4, 256, 0, stream>>>(h, hl, attn_l, attn_r, beta, aw, Aarr, Barr);
    count_kernel<<<EE / 256, 256, 0, stream>>>(dst, cnt);
    scan1_kernel<<<SCAN_NB, 256, 0, stream>>>(cnt, partials);
    scan2_kernel<<<1, 512, 0, stream>>>(partials);
    scan3_kernel<<<SCAN_NB, 256, 0, stream>>>(cnt, partials, row, cur);
    bucket_kernel<<<EE / 256, 256, 0, stream>>>(src, dst, wts, cur, csr_src, csr_wts);

    // edge math in CSR order: dst side in registers, only src gathers random
    edge2_kernel<<<NN / 4, 256, 0, stream>>>(row, csr_src, csr_wts, h, hl, Aarr, Barr,
                                             s_attn, beta, aw, ew, deg_s, deg_d, lp_part);
    reduce_kernel<<<1, 256, 0, stream>>>(lp_part, NN / 4, lp);

    wnorm_csr_kernel<<<NN / 16, 256, 0, stream>>>(row, csr_src, ew, deg_s, deg_d, theta, csr_w);

    // cast h -> bf16 gather source
    cast_bf_kernel<<<(NN * 64 / 4 + 255) / 256, 256, 0, stream>>>(h, h_bf, NN * 64 / 4);

    const short* fin = h_bf;
    short* bufs[2] = {fpA_bf, fpB_bf};
    for (int it = 0; it < 7; ++it) {
        short* fo = bufs[it & 1];
        prop_kernel<0><<<NN / 4, 256, 0, stream>>>(fin, h, row, csr_src, csr_w, fo, nullptr);
        fin = fo;
    }
    prop_kernel<1><<<NN / 4, 256, 0, stream>>>(fin, h, row, csr_src, csr_w, nullptr, out);
}

// Round 5
// 1160.622 us; speedup vs baseline: 1.5377x; 1.0828x over previous
//
#include <hip/hip_runtime.h>
#include <math.h>

#define NN 100000
#define EE 1600000
#define NFEATC 512
#define NHIDC 256
#define NCC 64
#define ALPHA_C 0.1f
#define NSLOPE_C 0.2f
#define SCAN_NB ((NN + 255) / 256)   // 391 blocks of 256 nodes

typedef __attribute__((ext_vector_type(8))) short short8;
typedef __attribute__((ext_vector_type(4))) short short4v;
typedef __attribute__((ext_vector_type(4))) float floatx4;

__device__ __forceinline__ short f2bf(float f) {
    unsigned u = __float_as_uint(f);
    unsigned r = (u + 0x7FFFu + ((u >> 16) & 1u)) >> 16;   // RNE
    return (short)r;
}
__device__ __forceinline__ float bf2f(short s) {
    return __uint_as_float(((unsigned)(unsigned short)s) << 16);
}

// ---------------- W_in cast to fragment-linear bf16 ----------------
// WB[((k>>5)*16 + (col>>4))*512 + ((k>>3)&3)*128 + (col&15)*8 + (k&7)]
// so a wave's B-fragment read (iter it, colfrag c) is 64 lanes x 16B contiguous.
__global__ __launch_bounds__(256)
void castWT_kernel(const float* __restrict__ W, short* __restrict__ WB)
{
    int k = blockIdx.x;      // 0..511
    int col = threadIdx.x;   // 0..255
    short v = f2bf(W[(size_t)k * NHIDC + col]);
    size_t idx = ((size_t)(k >> 5) * 16 + (col >> 4)) * 512
               + (size_t)((k >> 3) & 3) * 128 + (col & 15) * 8 + (k & 7);
    WB[idx] = v;
}

// ---------------- elementwise fp32 -> bf16 cast (vectorized 4/thread) ----------------
__global__ __launch_bounds__(256)
void cast_bf_kernel(const float* __restrict__ in, short* __restrict__ out, int n4)
{
    int i = blockIdx.x * 256 + threadIdx.x;
    if (i >= n4) return;
    float4 v = reinterpret_cast<const float4*>(in)[i];
    short4v o;
    o[0] = f2bf(v.x); o[1] = f2bf(v.y); o[2] = f2bf(v.z); o[3] = f2bf(v.w);
    reinterpret_cast<short4v*>(out)[i] = o;
}

// ---------------- gemm1: h1 = elu(x @ W_in) via bf16 MFMA ----------------
// B-frags direct from global (fragment-linear WB, L2-resident).
// A staged via double-buffered LDS, loads prefetched 1 iter ahead, 1 barrier/iter.
__global__ __launch_bounds__(256)
void gemm1_mfma_kernel(const float* __restrict__ x, const short* __restrict__ WB,
                       float* __restrict__ h1, int M)
{
    __shared__ short As[2][128][40];
    const int tid = threadIdx.x;
    const int bm = blockIdx.x * 128;
    const int wave = tid >> 6;
    const int lane = tid & 63;
    const int wm = wave >> 1;
    const int wn = wave & 1;
    const int l16 = lane & 15;
    const int quad = lane >> 4;

    floatx4 acc[4][8];
    #pragma unroll
    for (int i = 0; i < 4; ++i)
        #pragma unroll
        for (int j = 0; j < 8; ++j)
            acc[i][j] = (floatx4){0.f, 0.f, 0.f, 0.f};

    const int ar = tid >> 1;
    const int ah = tid & 1;
    const int xrow = bm + ar;
    const bool arow_ok = (xrow < M);
    const float* xp = x + (size_t)xrow * NFEATC + ah * 16;
    // per-lane B base: frag (it, ni) lives at + (it*16 + ni)*512
    const short* wbp = WB + (size_t)(wn * 8) * 512 + lane * 8;

    float4 a0, a1, a2, a3;

#define LOADA(kt)                                                         \
    if (arow_ok) {                                                        \
        a0 = *reinterpret_cast<const float4*>(xp + (kt) + 0);             \
        a1 = *reinterpret_cast<const float4*>(xp + (kt) + 4);             \
        a2 = *reinterpret_cast<const float4*>(xp + (kt) + 8);             \
        a3 = *reinterpret_cast<const float4*>(xp + (kt) + 12);            \
    } else {                                                              \
        a0 = a1 = a2 = a3 = make_float4(0.f, 0.f, 0.f, 0.f);             \
    }

#define CVTSTORE(buf)                                                     \
    {                                                                     \
        short8 s0, s1;                                                    \
        s0[0] = f2bf(a0.x); s0[1] = f2bf(a0.y); s0[2] = f2bf(a0.z); s0[3] = f2bf(a0.w); \
        s0[4] = f2bf(a1.x); s0[5] = f2bf(a1.y); s0[6] = f2bf(a1.z); s0[7] = f2bf(a1.w); \
        s1[0] = f2bf(a2.x); s1[1] = f2bf(a2.y); s1[2] = f2bf(a2.z); s1[3] = f2bf(a2.w); \
        s1[4] = f2bf(a3.x); s1[5] = f2bf(a3.y); s1[6] = f2bf(a3.z); s1[7] = f2bf(a3.w); \
        *reinterpret_cast<short8*>(&As[buf][ar][ah * 16 + 0]) = s0;       \
        *reinterpret_cast<short8*>(&As[buf][ar][ah * 16 + 8]) = s1;       \
    }

    // prologue: tile 0 into buf0, prefetch tile 1
    LOADA(0);
    CVTSTORE(0);
    LOADA(32);
    __syncthreads();

    for (int it = 0; it < 16; ++it) {
        const int cur = it & 1;
        short8 af[4];
        #pragma unroll
        for (int mi = 0; mi < 4; ++mi)
            af[mi] = *reinterpret_cast<const short8*>(&As[cur][wm * 64 + mi * 16 + l16][quad * 8]);
        short8 bfr[8];
        #pragma unroll
        for (int ni = 0; ni < 8; ++ni)
            bfr[ni] = *reinterpret_cast<const short8*>(wbp + ((size_t)(it * 16 + ni) << 9));
        #pragma unroll
        for (int mi = 0; mi < 4; ++mi)
            #pragma unroll
            for (int ni = 0; ni < 8; ++ni)
                acc[mi][ni] = __builtin_amdgcn_mfma_f32_16x16x32_bf16(af[mi], bfr[ni], acc[mi][ni], 0, 0, 0);
        if (it < 15) {
            CVTSTORE(1 - cur);          // consumes prefetched tile it+1
            if (it < 14) { LOADA((it + 2) * 32); }
        }
        __syncthreads();
    }
#undef LOADA
#undef CVTSTORE

    #pragma unroll
    for (int mi = 0; mi < 4; ++mi) {
        #pragma unroll
        for (int r = 0; r < 4; ++r) {
            int row = bm + wm * 64 + mi * 16 + quad * 4 + r;
            if (row >= M) continue;
            float* outp = h1 + (size_t)row * NHIDC + wn * 128 + l16;
            #pragma unroll
            for (int ni = 0; ni < 8; ++ni) {
                float v = acc[mi][ni][r];
                v = (v > 0.f) ? v : (expf(v) - 1.f);
                outp[ni * 16] = v;
            }
        }
    }
}

// ---------------- GEMM: C = act(A@B + bias), tile 64x64, KT=16, 256 thr, 4x4 micro ----------------
template<int ACT>
__global__ __launch_bounds__(256)
void gemm_kernel(const float* __restrict__ A, const float* __restrict__ B,
                 const float* __restrict__ bias, float* __restrict__ C,
                 int M, int K, int Ncols)
{
    __shared__ float As[16][68];
    __shared__ float Bs[16][64];
    const int tid = threadIdx.x;
    const int bm = blockIdx.x * 64;
    const int bn = blockIdx.y * 64;
    const int m0 = (tid & 15) * 4;
    const int n0 = (tid >> 4) * 4;
    float acc[4][4] = {};

    const int am = bm + (tid >> 2);
    const int ak = (tid & 3) * 4;
    const int bk = tid >> 4;
    const int bn4 = bn + (tid & 15) * 4;

    for (int kt = 0; kt < K; kt += 16) {
        float4 av;
        if (am < M) av = *reinterpret_cast<const float4*>(A + (size_t)am * K + kt + ak);
        else        av = make_float4(0.f, 0.f, 0.f, 0.f);
        float4 bv = *reinterpret_cast<const float4*>(B + (size_t)(kt + bk) * Ncols + bn4);
        __syncthreads();
        As[ak + 0][tid >> 2] = av.x;
        As[ak + 1][tid >> 2] = av.y;
        As[ak + 2][tid >> 2] = av.z;
        As[ak + 3][tid >> 2] = av.w;
        *reinterpret_cast<float4*>(&Bs[bk][(tid & 15) * 4]) = bv;
        __syncthreads();
        #pragma unroll
        for (int k = 0; k < 16; ++k) {
            float4 a4 = *reinterpret_cast<const float4*>(&As[k][m0]);
            float4 b4 = *reinterpret_cast<const float4*>(&Bs[k][n0]);
            float a_[4] = {a4.x, a4.y, a4.z, a4.w};
            float b_[4] = {b4.x, b4.y, b4.z, b4.w};
            #pragma unroll
            for (int i = 0; i < 4; ++i)
                #pragma unroll
                for (int j = 0; j < 4; ++j)
                    acc[i][j] = fmaf(a_[i], b_[j], acc[i][j]);
        }
    }

    float bvals[4] = {0.f, 0.f, 0.f, 0.f};
    if (bias) {
        bvals[0] = bias[bn + n0 + 0]; bvals[1] = bias[bn + n0 + 1];
        bvals[2] = bias[bn + n0 + 2]; bvals[3] = bias[bn + n0 + 3];
    }
    #pragma unroll
    for (int i = 0; i < 4; ++i) {
        int r = bm + m0 + i;
        if (r >= M) break;
        float v[4];
        #pragma unroll
        for (int j = 0; j < 4; ++j) {
            float t = acc[i][j] + bvals[j];
            if (ACT == 1) t = (t > 0.f) ? t : (expf(t) - 1.f);
            v[j] = t;
        }
        float4 o = make_float4(v[0], v[1], v[2], v[3]);
        *reinterpret_cast<float4*>(C + (size_t)r * Ncols + bn + n0) = o;
    }
}

// ---------------- per-node scalars: A = el - bw(w0*nh+w1*nl), B = er - bw(w0*nh+w1*nl) ----------------
__global__ __launch_bounds__(256)
void attn2_kernel(const float* __restrict__ h, const float* __restrict__ hl,
                  const float* __restrict__ attn_l, const float* __restrict__ attn_r,
                  const float* __restrict__ beta, const float* __restrict__ aw,
                  float* __restrict__ A, float* __restrict__ B)
{
    int node = blockIdx.x * 4 + (threadIdx.x >> 6);
    int lane = threadIdx.x & 63;
    if (node >= NN) return;
    float v = h[(size_t)node * 64 + lane];
    float u = hl[(size_t)node * 64 + lane];
    float lr = (v > 0.f) ? v : NSLOPE_C * v;
    float a = lr * attn_l[lane];
    float b = lr * attn_r[lane];
    float nh = v * v;
    float nl = u * u;
    #pragma unroll
    for (int m = 1; m < 64; m <<= 1) {
        a += __shfl_xor(a, m);
        b += __shfl_xor(b, m);
        nh += __shfl_xor(nh, m);
        nl += __shfl_xor(nl, m);
    }
    if (lane == 0) {
        float betaw = 2.f / (expf(-beta[0]) + 1.f);
        float a0 = aw[0], a1 = aw[1];
        float mxw = fmaxf(a0, a1);
        float e0 = expf(a0 - mxw), e1 = expf(a1 - mxw);
        float inv = 1.f / (e0 + e1);
        float t = betaw * (e0 * inv * nh + e1 * inv * nl);
        A[node] = a - t;
        B[node] = b - t;
    }
}

// ---------------- CSR build ----------------
__global__ __launch_bounds__(256)
void count_kernel(const int* __restrict__ dst, int* __restrict__ cnt)
{
    int e = blockIdx.x * 256 + threadIdx.x;
    if (e < EE) atomicAdd(cnt + dst[e], 1);
}

// ---- 3-phase parallel exclusive scan over cnt[NN] -> row[], cur[] ----
__global__ __launch_bounds__(256)
void scan1_kernel(const int* __restrict__ cnt, int* __restrict__ partials)
{
    int i = blockIdx.x * 256 + threadIdx.x;
    int v = (i < NN) ? cnt[i] : 0;
    #pragma unroll
    for (int m = 1; m < 64; m <<= 1) v += __shfl_xor(v, m);
    __shared__ int sred[4];
    if ((threadIdx.x & 63) == 0) sred[threadIdx.x >> 6] = v;
    __syncthreads();
    if (threadIdx.x == 0)
        partials[blockIdx.x] = sred[0] + sred[1] + sred[2] + sred[3];
}

__global__ __launch_bounds__(512)
void scan2_kernel(int* __restrict__ partials)
{
    __shared__ int s[512];
    int t = threadIdx.x;
    int v = (t < SCAN_NB) ? partials[t] : 0;
    s[t] = v;
    __syncthreads();
    #pragma unroll
    for (int off = 1; off < 512; off <<= 1) {
        int add = (t >= off) ? s[t - off] : 0;
        __syncthreads();
        s[t] += add;
        __syncthreads();
    }
    if (t < SCAN_NB) partials[t] = s[t] - v;   // exclusive
}

__global__ __launch_bounds__(256)
void scan3_kernel(const int* __restrict__ cnt, const int* __restrict__ partials,
                  int* __restrict__ row, int* __restrict__ cur)
{
    __shared__ int s[256];
    int t = threadIdx.x;
    int i = blockIdx.x * 256 + t;
    int v = (i < NN) ? cnt[i] : 0;
    s[t] = v;
    __syncthreads();
    #pragma unroll
    for (int off = 1; off < 256; off <<= 1) {
        int add = (t >= off) ? s[t - off] : 0;
        __syncthreads();
        s[t] += add;
        __syncthreads();
    }
    int r = partials[blockIdx.x] + s[t] - v;   // exclusive prefix
    if (i < NN) { row[i] = r; cur[i] = r; }
    if (i == NN - 1) row[NN] = r + v;
}

// bucket: scatter src index + original edge weight into CSR order (by dst)
__global__ __launch_bounds__(256)
void bucket_kernel(const int* __restrict__ src, const int* __restrict__ dst,
                   const float* __restrict__ wts, int* __restrict__ cur,
                   int* __restrict__ csr_src, float* __restrict__ csr_wts)
{
    int e = blockIdx.x * 256 + threadIdx.x;
    if (e >= EE) return;
    int d = dst[e];
    int pos = atomicAdd(cur + d, 1);
    csr_src[pos] = src[e];
    csr_wts[pos] = wts[e];
}

// ---------------- edge computation, CSR order, norm-decomposed, 2x pipelined ----------------
__global__ __launch_bounds__(256)
void edge2_kernel(const int* __restrict__ row, const int* __restrict__ csr_src,
                  const float* __restrict__ csr_wts,
                  const float* __restrict__ h, const float* __restrict__ hl,
                  const float* __restrict__ A, const float* __restrict__ B,
                  const float* __restrict__ s_attn, const float* __restrict__ beta,
                  const float* __restrict__ aw,
                  float* __restrict__ ew, float* __restrict__ deg_s,
                  float* __restrict__ deg_d, float* __restrict__ lp_part)
{
    int node = blockIdx.x * 4 + (threadIdx.x >> 6);
    int lane = threadIdx.x & 63;
    int sub = lane >> 4;      // 4 edges in flight per wave (x2 unroll = 8)
    int f = lane & 15;        // 16 lanes x float4 = full 64-feature row
    float lp_p = 0.f;
    if (node < NN) {
        int b = row[node], en = row[node + 1];
        float betaw = 2.f / (expf(-beta[0]) + 1.f);
        float a0 = aw[0], a1 = aw[1];
        float mxw = fmaxf(a0, a1);
        float e0 = expf(a0 - mxw), e1 = expf(a1 - mxw);
        float inv = 1.f / (e0 + e1);
        float c0 = 2.f * betaw * e0 * inv;
        float c1 = 2.f * betaw * e1 * inv;
        const float4 hd = *reinterpret_cast<const float4*>(h  + (size_t)node * 64 + f * 4);
        const float4 ld = *reinterpret_cast<const float4*>(hl + (size_t)node * 64 + f * 4);
        const float4 sa = *reinterpret_cast<const float4*>(s_attn + f * 4);
        float4 P = make_float4(c0 * hd.x, c0 * hd.y, c0 * hd.z, c0 * hd.w);
        float4 Q = make_float4(sa.x * ld.x, sa.y * ld.y, sa.z * ld.z, sa.w * ld.w);
        float Bd = B[node];
        float degd = 0.f;
        int e = b + sub;
        for (; e + 4 < en; e += 8) {
            int s1 = csr_src[e];
            int s2 = csr_src[e + 4];
            const float4 hs1 = *reinterpret_cast<const float4*>(h  + (size_t)s1 * 64 + f * 4);
            const float4 ls1 = *reinterpret_cast<const float4*>(hl + (size_t)s1 * 64 + f * 4);
            const float4 hs2 = *reinterpret_cast<const float4*>(h  + (size_t)s2 * 64 + f * 4);
            const float4 ls2 = *reinterpret_cast<const float4*>(hl + (size_t)s2 * 64 + f * 4);
            float r1 = hs1.x * P.x + hs1.y * P.y + hs1.z * P.z + hs1.w * P.w
                     + ls1.x * Q.x + ls1.y * Q.y + ls1.z * Q.z + ls1.w * Q.w;
            float d31 = ls1.x * ld.x + ls1.y * ld.y + ls1.z * ld.z + ls1.w * ld.w;
            float r2 = hs2.x * P.x + hs2.y * P.y + hs2.z * P.z + hs2.w * P.w
                     + ls2.x * Q.x + ls2.y * Q.y + ls2.z * Q.z + ls2.w * Q.w;
            float d32 = ls2.x * ld.x + ls2.y * ld.y + ls2.z * ld.z + ls2.w * ld.w;
            #pragma unroll
            for (int m = 1; m < 16; m <<= 1) {
                r1  += __shfl_xor(r1, m);
                d31 += __shfl_xor(d31, m);
                r2  += __shfl_xor(r2, m);
                d32 += __shfl_xor(d32, m);
            }
            if (f == 0) {
                float v1 = expf(A[s1] + Bd + r1 + c1 * d31) + 1e-9f;
                ew[e] = v1;
                atomicAdd(deg_s + s1, v1);
                degd += v1;
                lp_p += d31 * csr_wts[e];
                float v2 = expf(A[s2] + Bd + r2 + c1 * d32) + 1e-9f;
                ew[e + 4] = v2;
                atomicAdd(deg_s + s2, v2);
                degd += v2;
                lp_p += d32 * csr_wts[e + 4];
            }
        }
        if (e < en) {
            int s1 = csr_src[e];
            const float4 hs1 = *reinterpret_cast<const float4*>(h  + (size_t)s1 * 64 + f * 4);
            const float4 ls1 = *reinterpret_cast<const float4*>(hl + (size_t)s1 * 64 + f * 4);
            float r1 = hs1.x * P.x + hs1.y * P.y + hs1.z * P.z + hs1.w * P.w
                     + ls1.x * Q.x + ls1.y * Q.y + ls1.z * Q.z + ls1.w * Q.w;
            float d31 = ls1.x * ld.x + ls1.y * ld.y + ls1.z * ld.z + ls1.w * ld.w;
            #pragma unroll
            for (int m = 1; m < 16; m <<= 1) {
                r1  += __shfl_xor(r1, m);
                d31 += __shfl_xor(d31, m);
            }
            if (f == 0) {
                float v1 = expf(A[s1] + Bd + r1 + c1 * d31) + 1e-9f;
                ew[e] = v1;
                atomicAdd(deg_s + s1, v1);
                degd += v1;
                lp_p += d31 * csr_wts[e];
            }
        }
        #pragma unroll
        for (int m = 16; m < 64; m <<= 1) degd += __shfl_xor(degd, m);
        if (lane == 0) deg_d[node] = degd;
    }
    #pragma unroll
    for (int m = 16; m < 64; m <<= 1) lp_p += __shfl_xor(lp_p, m);
    __shared__ float lred[4];
    if ((threadIdx.x & 63) == 0) lred[threadIdx.x >> 6] = lp_p;
    __syncthreads();
    if (threadIdx.x == 0) lp_part[blockIdx.x] = lred[0] + lred[1] + lred[2] + lred[3];
}

// ---------------- reduce lp partials ----------------
__global__ __launch_bounds__(256)
void reduce_kernel(const float* __restrict__ part, int n, float* __restrict__ out)
{
    float s = 0.f;
    for (int i = threadIdx.x; i < n; i += 256) s += part[i];
    #pragma unroll
    for (int m = 1; m < 64; m <<= 1) s += __shfl_xor(s, m);
    __shared__ float sd[4];
    if ((threadIdx.x & 63) == 0) sd[threadIdx.x >> 6] = s;
    __syncthreads();
    if (threadIdx.x == 0) out[0] = sd[0] + sd[1] + sd[2] + sd[3];
}

// ---------------- edge normalization, CSR order (sequential) ----------------
__global__ __launch_bounds__(256)
void wnorm_csr_kernel(const int* __restrict__ row, const int* __restrict__ csr_src,
                      const float* __restrict__ ew, const float* __restrict__ deg_s,
                      const float* __restrict__ deg_d, const float* __restrict__ theta,
                      float* __restrict__ csr_w)
{
    int node = blockIdx.x * 16 + (threadIdx.x >> 4);
    int f = threadIdx.x & 15;
    if (node >= NN) return;
    int b = row[node], en = row[node + 1];
    float perm = 1e-9f / (expf(-theta[0]) + 1.f);
    float dr = rsqrtf(deg_d[node]);
    for (int e = b + f; e < en; e += 16) {
        float v = ew[e] * rsqrtf(deg_s[csr_src[e]]) * dr + perm;
        csr_w[e] = (1.0f - ALPHA_C) * v;
    }
}

// ---------------- propagation: 2 nodes/wave, 4 edge-slots x 8 feature-lanes ----------------
template<int FINAL>
__global__ __launch_bounds__(256)
void prop_kernel(const short* __restrict__ fin, const float* __restrict__ h,
                 const int* __restrict__ row, const int* __restrict__ csr_src,
                 const float* __restrict__ csr_w,
                 short* __restrict__ foutb, float* __restrict__ outf)
{
    int node = blockIdx.x * 8 + (threadIdx.x >> 5);
    int l32 = threadIdx.x & 31;
    int sub = l32 >> 3;   // 4 edge slots per node
    int f = l32 & 7;      // 8 features-lanes x short8
    if (node >= NN) return;
    int b = row[node], en = row[node + 1];
    float acc[8] = {};
    int e = b + sub;
    for (; e + 4 < en; e += 8) {
        int s1 = csr_src[e];
        float w1 = csr_w[e];
        int s2 = csr_src[e + 4];
        float w2 = csr_w[e + 4];
        short8 v1 = *reinterpret_cast<const short8*>(fin + (size_t)s1 * 64 + f * 8);
        short8 v2 = *reinterpret_cast<const short8*>(fin + (size_t)s2 * 64 + f * 8);
        #pragma unroll
        for (int i = 0; i < 8; ++i)
            acc[i] = fmaf(w1, bf2f(v1[i]), acc[i]);
        #pragma unroll
        for (int i = 0; i < 8; ++i)
            acc[i] = fmaf(w2, bf2f(v2[i]), acc[i]);
    }
    if (e < en) {
        int s1 = csr_src[e];
        float w1 = csr_w[e];
        short8 v1 = *reinterpret_cast<const short8*>(fin + (size_t)s1 * 64 + f * 8);
        #pragma unroll
        for (int i = 0; i < 8; ++i)
            acc[i] = fmaf(w1, bf2f(v1[i]), acc[i]);
    }
    #pragma unroll
    for (int m = 8; m < 32; m <<= 1)
        #pragma unroll
        for (int i = 0; i < 8; ++i)
            acc[i] += __shfl_xor(acc[i], m);
    if (sub == 0) {
        const float4 h0 = *reinterpret_cast<const float4*>(h + (size_t)node * 64 + f * 8 + 0);
        const float4 h1v = *reinterpret_cast<const float4*>(h + (size_t)node * 64 + f * 8 + 4);
        float o[8];
        o[0] = fmaf(ALPHA_C, h0.x, acc[0]);
        o[1] = fmaf(ALPHA_C, h0.y, acc[1]);
        o[2] = fmaf(ALPHA_C, h0.z, acc[2]);
        o[3] = fmaf(ALPHA_C, h0.w, acc[3]);
        o[4] = fmaf(ALPHA_C, h1v.x, acc[4]);
        o[5] = fmaf(ALPHA_C, h1v.y, acc[5]);
        o[6] = fmaf(ALPHA_C, h1v.z, acc[6]);
        o[7] = fmaf(ALPHA_C, h1v.w, acc[7]);
        if (!FINAL) {
            short8 ob;
            #pragma unroll
            for (int i = 0; i < 8; ++i) ob[i] = f2bf(o[i]);
            *reinterpret_cast<short8*>(foutb + (size_t)node * 64 + f * 8) = ob;
        } else {
            float ev[8];
            #pragma unroll
            for (int i = 0; i < 8; ++i)
                ev[i] = (o[i] > 0.f) ? o[i] : (expf(o[i]) - 1.f);
            float mx = ev[0];
            #pragma unroll
            for (int i = 1; i < 8; ++i) mx = fmaxf(mx, ev[i]);
            #pragma unroll
            for (int m = 1; m < 8; m <<= 1) mx = fmaxf(mx, __shfl_xor(mx, m));
            float s = 0.f;
            #pragma unroll
            for (int i = 0; i < 8; ++i) s += expf(ev[i] - mx);
            #pragma unroll
            for (int m = 1; m < 8; m <<= 1) s += __shfl_xor(s, m);
            float ls = mx + logf(s);
            float4 o0 = make_float4(ev[0] - ls, ev[1] - ls, ev[2] - ls, ev[3] - ls);
            float4 o1 = make_float4(ev[4] - ls, ev[5] - ls, ev[6] - ls, ev[7] - ls);
            *reinterpret_cast<float4*>(outf + (size_t)node * 64 + f * 8 + 0) = o0;
            *reinterpret_cast<float4*>(outf + (size_t)node * 64 + f * 8 + 4) = o1;
        }
    }
}

extern "C" void kernel_launch(void* const* d_in, const int* in_sizes, int n_in,
                              void* d_out, int out_size, void* d_ws, size_t ws_size,
                              hipStream_t stream)
{
    const float* x      = (const float*)d_in[0];
    const int*   src    = (const int*)d_in[1];
    const int*   dst    = (const int*)d_in[2];
    const float* wts    = (const float*)d_in[3];
    const float* latp   = (const float*)d_in[4];
    const float* W_in   = (const float*)d_in[5];
    const float* W_out  = (const float*)d_in[6];
    const float* Ws1    = (const float*)d_in[7];
    const float* b1     = (const float*)d_in[8];
    const float* Ws2    = (const float*)d_in[9];
    const float* b2     = (const float*)d_in[10];
    const float* attn_l = (const float*)d_in[11];
    const float* attn_r = (const float*)d_in[12];
    const float* s_attn = (const float*)d_in[13];
    const float* beta   = (const float*)d_in[14];
    const float* theta  = (const float*)d_in[15];
    const float* aw     = (const float*)d_in[16];

    float* out = (float*)d_out;
    float* lp  = out + (size_t)NN * 64;

    char* w8 = (char*)d_ws;
    size_t off = 0;
    auto alloc = [&](size_t bytes) -> char* {
        char* p = w8 + off;
        off += (bytes + 255) / 256 * 256;
        return p;
    };
    float* big     = (float*)alloc((size_t)NN * 256 * 4);
    float* h1      = big;
    float* hl_tmp  = big;
    short* h_bf    = (short*)big;
    short* fpA_bf  = (short*)big + (size_t)NN * 64;
    short* fpB_bf  = (short*)big + (size_t)NN * 64 * 2;
    float* csr_wts = (float*)((short*)big + (size_t)NN * 64 * 3);
    float* h      = (float*)alloc((size_t)NN * 64 * 4);
    float* hl     = (float*)alloc((size_t)NN * 64 * 4);
    float* ew     = (float*)alloc((size_t)EE * 4);   // ew in CSR order
    float* Aarr   = (float*)alloc((size_t)NN * 4);
    float* Barr   = (float*)alloc((size_t)NN * 4);
    float* deg_s  = (float*)alloc((size_t)NN * 4);
    float* deg_d  = (float*)alloc((size_t)NN * 4);
    int*   cnt    = (int*)alloc((size_t)NN * 4);
    int*   row    = (int*)alloc((size_t)(NN + 1) * 4);
    int*   cur    = (int*)alloc((size_t)NN * 4);
    int*   csr_src= (int*)alloc((size_t)EE * 4);
    float* csr_w  = (float*)alloc((size_t)EE * 4);
    float* lp_part= (float*)alloc((size_t)100000 * 4);
    int*   partials=(int*)alloc((size_t)SCAN_NB * 4);
    short* WB     = (short*)alloc((size_t)NHIDC * NFEATC * 2);

    hipMemsetAsync(cnt,   0, (size_t)NN * 4, stream);
    hipMemsetAsync(deg_s, 0, (size_t)NN * 4, stream);

    const int MB = (NN + 63) / 64;  // 1563

    // h1 = elu(x @ W_in)  -- bf16 MFMA, fragment-linear B from global
    castWT_kernel<<<NFEATC, 256, 0, stream>>>(W_in, WB);
    gemm1_mfma_kernel<<<(NN + 127) / 128, 256, 0, stream>>>(x, WB, h1, NN);

    gemm_kernel<0><<<dim3(MB, 1), 256, 0, stream>>>(h1, W_out, nullptr, h, NN, NHIDC, NCC);
    gemm_kernel<1><<<dim3(MB, 1), 256, 0, stream>>>(latp, Ws1, b1, hl_tmp, NN, NCC, NCC);
    gemm_kernel<1><<<dim3(MB, 1), 256, 0, stream>>>(hl_tmp, Ws2, b2, hl, NN, NCC, NCC);

    attn2_kernel<<<NN / 4, 256, 0, stream>>>(h, hl, attn_l, attn_r, beta, aw, Aarr, Barr);
    count_kernel<<<EE / 256, 256, 0, stream>>>(dst, cnt);
    scan1_kernel<<<SCAN_NB, 256, 0, stream>>>(cnt, partials);
    scan2_kernel<<<1, 512, 0, stream>>>(partials);
    scan3_kernel<<<SCAN_NB, 256, 0, stream>>>(cnt, partials, row, cur);
    bucket_kernel<<<EE / 256, 256, 0, stream>>>(src, dst, wts, cur, csr_src, csr_wts);

    edge2_kernel<<<NN / 4, 256, 0, stream>>>(row, csr_src, csr_wts, h, hl, Aarr, Barr,
                                             s_attn, beta, aw, ew, deg_s, deg_d, lp_part);
    reduce_kernel<<<1, 256, 0, stream>>>(lp_part, NN / 4, lp);

    wnorm_csr_kernel<<<NN / 16, 256, 0, stream>>>(row, csr_src, ew, deg_s, deg_d, theta, csr_w);

    // cast h -> bf16 gather source
    cast_bf_kernel<<<(NN * 64 / 4 + 255) / 256, 256, 0, stream>>>(h, h_bf, NN * 64 / 4);

    const short* fin = h_bf;
    short* bufs[2] = {fpA_bf, fpB_bf};
    for (int it = 0; it < 7; ++it) {
        short* fo = bufs[it & 1];
        prop_kernel<0><<<NN / 8, 256, 0, stream>>>(fin, h, row, csr_src, csr_w, fo, nullptr);
        fin = fo;
    }
    prop_kernel<1><<<NN / 8, 256, 0, stream>>>(fin, h, row, csr_src, csr_w, nullptr, out);
}